// Round 7
// baseline (209.724 us; speedup 1.0000x reference)
//
#include <hip/hip_runtime.h>
#include <hip/hip_bf16.h>

#define DEVI __device__ __forceinline__

typedef __attribute__((ext_vector_type(8))) short s16x8;
typedef __attribute__((ext_vector_type(4))) short s16x4;
typedef __attribute__((ext_vector_type(4))) float f32x4;

// ---- problem constants ----
// x: (8, 384, 32, 32); heads=8, dk=32, dv=64; N=1024 tokens; Cqk=256, Cv=512
#define LOG2E 1.4426950408889634f

DEVI short f2bs(float f) {  // fp32 -> bf16 bits (RNE)
    unsigned u = __builtin_bit_cast(unsigned, f);
    unsigned r = (u + 0x7fffu + ((u >> 16) & 1u)) >> 16;
    return (short)r;
}

DEVI f32x4 mfma16(s16x8 a, s16x8 b, f32x4 c) {
    return __builtin_amdgcn_mfma_f32_16x16x32_bf16(a, b, c, 0, 0, 0);
}

// ---------------- prep: x (b,c,n) fp32 -> xt (b,n,c) bf16 ----------------
__global__ __launch_bounds__(256) void k_prep_x(const float* __restrict__ x,
                                                short* __restrict__ xt) {
    __shared__ float tile[32][33];
    const int ct = blockIdx.x, nt = blockIdx.y, b = blockIdx.z;
    const int t = threadIdx.x;
    {
        const int j = t & 31, i0 = (t >> 5) * 4;
        const float* src = x + ((size_t)b * 384 + (size_t)ct * 32) * 1024 + nt * 32;
#pragma unroll
        for (int ii = 0; ii < 4; ++ii)
            tile[i0 + ii][j] = src[(size_t)(i0 + ii) * 1024 + j];
    }
    __syncthreads();
    {
        const int ii = t & 31, j0 = (t >> 5) * 4;
        short* dst = xt + ((size_t)b * 1024 + (size_t)nt * 32) * 384 + ct * 32;
#pragma unroll
        for (int jj = 0; jj < 4; ++jj)
            dst[(size_t)(j0 + jj) * 384 + ii] = f2bs(tile[ii][j0 + jj]);
    }
}

// ---------------- prep: weights fp32 -> bf16, plus BN fold ----------------
// Q-channel BN scale/shift are folded with LOG2E so softmax exp becomes exp2.
__global__ __launch_bounds__(256) void k_prep_w(
    const float* __restrict__ wq, const float* __restrict__ wk,
    const float* __restrict__ wv, const float* __restrict__ wp,
    short* __restrict__ wqkv, short* __restrict__ wpb,
    const float* gq, const float* bq, const float* mq, const float* vq,
    const float* gk, const float* bk, const float* mk, const float* vk,
    const float* gv, const float* bv, const float* mv, const float* vv,
    const float* gp, const float* bp, const float* mp, const float* vp,
    float* s_qkv, float* t_qkv, float* s_p, float* t_p) {
    int i = blockIdx.x * 256 + threadIdx.x;
    if (i < 1024) {
        const float *g, *bb, *mm, *vv_;
        int o = i;
        float post = 1.0f;
        if (i < 256)      { g = gq; bb = bq; mm = mq; vv_ = vq; post = LOG2E; }
        else if (i < 512) { g = gk; bb = bk; mm = mk; vv_ = vk; o = i - 256; }
        else              { g = gv; bb = bv; mm = mv; vv_ = vv; o = i - 512; }
        float s = g[o] * rsqrtf(vv_[o] + 1e-5f);
        s_qkv[i] = s * post;
        t_qkv[i] = (bb[o] - mm[o] * s) * post;
        if (i < 384) {
            float sp = gp[i] * rsqrtf(vp[i] + 1e-5f);
            s_p[i] = sp;
            t_p[i] = bp[i] - mp[i] * sp;
        }
    }
    const int NQKV = 1024 * 384;
    if (i < NQKV) {
        int o = i / 384;
        float v;
        if (o < 256)      v = wq[i];
        else if (o < 512) v = wk[i - 256 * 384];
        else              v = wv[i - 512 * 384];
        wqkv[i] = f2bs(v);
    } else {
        int j = i - NQKV;
        if (j < 384 * 512) wpb[j] = f2bs(wp[j]);
    }
}

// ---------------- QKV GEMM: [1024ch x 384] x [384 x 8192] + BN, layout-split ----------------
// Qw: [b][h][n][32]  Kw: [b][h][m][32]  Vw: [b][h][e][1024]
// K-loop phase-rotated per wave (commutative sum) + register double-buffer.
__global__ __launch_bounds__(256) void k_gemm_qkv(
    const short* __restrict__ wqkv, const short* __restrict__ xt,
    const float* __restrict__ s_qkv, const float* __restrict__ t_qkv,
    short* __restrict__ Qw, short* __restrict__ Kw, short* __restrict__ Vw) {
    const int t = threadIdx.x, lane = t & 63, w = t >> 6;
    const int g = lane >> 4, l15 = lane & 15;
    const int mb = blockIdx.x, jb = blockIdx.y;
    const int m_base = mb * 128 + (w >> 1) * 64;
    const int j_base = jb * 128 + (w & 1) * 64;
    const int phase = ((w + jb) & 3) * 3;  // {0,3,6,9}: de-phase co-resident waves

    f32x4 acc[4][4];
#pragma unroll
    for (int mi = 0; mi < 4; ++mi)
#pragma unroll
        for (int ni = 0; ni < 4; ++ni) acc[mi][ni] = f32x4{0.f, 0.f, 0.f, 0.f};

    const short* Arow = wqkv + (size_t)(m_base + l15) * 384 + 8 * g;
    const short* Brow = xt + (size_t)(j_base + l15) * 384 + 8 * g;

    s16x8 aA[4], bA[4], aB[4], bB[4];
#pragma unroll
    for (int i = 0; i < 4; ++i) {
        aA[i] = *(const s16x8*)(Arow + (size_t)i * 16 * 384 + phase * 32);
        bA[i] = *(const s16x8*)(Brow + (size_t)i * 16 * 384 + phase * 32);
    }
    auto qbody = [&](s16x8 (&ac)[4], s16x8 (&bc)[4], s16x8 (&an)[4], s16x8 (&bn)[4], int it) {
        if (it < 11) {
            int ksn = it + 1 + phase;
            if (ksn >= 12) ksn -= 12;
#pragma unroll
            for (int i = 0; i < 4; ++i) {
                an[i] = *(const s16x8*)(Arow + (size_t)i * 16 * 384 + ksn * 32);
                bn[i] = *(const s16x8*)(Brow + (size_t)i * 16 * 384 + ksn * 32);
            }
        }
#pragma unroll
        for (int mi = 0; mi < 4; ++mi)
#pragma unroll
            for (int ni = 0; ni < 4; ++ni)
                acc[mi][ni] = mfma16(ac[mi], bc[ni], acc[mi][ni]);
    };
#pragma unroll
    for (int i2 = 0; i2 < 6; ++i2) {
        qbody(aA, bA, aB, bB, 2 * i2);
        qbody(aB, bB, aA, bA, 2 * i2 + 1);
    }

#pragma unroll
    for (int mi = 0; mi < 4; ++mi) {
        const int o0 = m_base + 16 * mi;
#pragma unroll
        for (int ni = 0; ni < 4; ++ni) {
            const int j = j_base + 16 * ni + l15;
            const int bb = j >> 10, n = j & 1023;
#pragma unroll
            for (int r = 0; r < 4; ++r) {
                const int o = o0 + 4 * g + r;
                float val = acc[mi][ni][r] * s_qkv[o] + t_qkv[o];
                short bv = f2bs(val);
                if (o0 < 256) {
                    int h = o >> 5, d = o & 31;
                    Qw[(((size_t)bb * 8 + h) * 1024 + n) * 32 + d] = bv;
                } else if (o0 < 512) {
                    int o2 = o - 256;
                    int h = o2 >> 5, d = o2 & 31;
                    Kw[(((size_t)bb * 8 + h) * 1024 + n) * 32 + d] = bv;
                } else {
                    int o2 = o - 512;
                    int h = o2 >> 6, e = o2 & 63;
                    Vw[(((size_t)bb * 8 + h) * 64 + e) * 1024 + n] = bv;
                }
            }
        }
    }
}

// ---------------- attention per (b,h): register-only flash (no-max), LDS-free ----------------
// 32 q-rows per wave, 4 waves/block; grid = 64 bh * 8 rb = 512 blocks, XCD-grouped.
// Permuted-K trick (R6): S^T D-layout == PV B-layout, P stays in registers.
// NEW (R7): per-wave phase rotation of the KV loop (order-free sum) breaks the
// phase-locked stall across co-resident waves; explicit next-tile K/V dbuf.
__global__ __launch_bounds__(256, 2) void k_attn(const short* __restrict__ Qw,
                                                 const short* __restrict__ Kw,
                                                 const short* __restrict__ Vw,
                                                 short* __restrict__ Ow) {
    const int t = threadIdx.x, lane = t & 63, w = t >> 6;
    const int g = lane >> 4, l15 = lane & 15;
    // blockIdx.x = (bh&7) + 8*(rb + 8*(bh>>3)) => all 8 rb of one bh on one XCD
    const int low3 = blockIdx.x & 7;
    const int mid = blockIdx.x >> 3;
    const int rb = mid & 7;
    const int bh = ((mid >> 3) << 3) | low3;
    const int n_base = rb * 128 + w * 32;
    const int phase = (rb * 4 + w) & 15;  // de-phase co-resident waves
    const short* Qb = Qw + (size_t)bh * (1024 * 32);
    const short* Kb = Kw + (size_t)bh * (1024 * 32);
    const short* Vb = Vw + (size_t)bh * (64 * 1024);

    s16x8 qf[2];
#pragma unroll
    for (int i = 0; i < 2; ++i)
        qf[i] = *(const s16x8*)(Qb + (size_t)(n_base + 16 * i + l15) * 32 + 8 * g);

    // permuted K base row within each 64-tile
    const int krow = 8 * (l15 >> 2) + (l15 & 3);
    const short* Kbase = Kb + (size_t)krow * 32 + 8 * g;

    f32x4 oacc[2][4];
#pragma unroll
    for (int niq = 0; niq < 2; ++niq)
#pragma unroll
        for (int ei = 0; ei < 4; ++ei) oacc[niq][ei] = f32x4{0.f, 0.f, 0.f, 0.f};
    float l_part[2] = {0.f, 0.f};

    s16x8 kfA[4], vbA[2][4], kfB[4], vbB[2][4];

    auto load_tile = [&](s16x8 (&kf)[4], s16x8 (&vb)[2][4], int m0) {
        kf[0] = *(const s16x8*)(Kbase + (size_t)(m0 + 0) * 32);
        kf[1] = *(const s16x8*)(Kbase + (size_t)(m0 + 4) * 32);
        kf[2] = *(const s16x8*)(Kbase + (size_t)(m0 + 32) * 32);
        kf[3] = *(const s16x8*)(Kbase + (size_t)(m0 + 36) * 32);
#pragma unroll
        for (int ki = 0; ki < 2; ++ki)
#pragma unroll
            for (int ei = 0; ei < 4; ++ei)
                vb[ki][ei] = *(const s16x8*)(Vb + (size_t)(16 * ei + l15) * 1024 + m0 + 32 * ki + 8 * g);
    };

    auto body = [&](s16x8 (&kfc)[4], s16x8 (&vbc)[2][4],
                    s16x8 (&kfn)[4], s16x8 (&vbn)[2][4], int it) {
        // S^T for current tile: st[mik][niq][r] = S[m0 + 8g + r + {0,4,32,36}[mik]][...]
        f32x4 st[4][2];
#pragma unroll
        for (int mik = 0; mik < 4; ++mik)
#pragma unroll
            for (int niq = 0; niq < 2; ++niq)
                st[mik][niq] = mfma16(kfc[mik], qf[niq], f32x4{0.f, 0.f, 0.f, 0.f});
        // issue next-tile loads (consumed next iteration)
        if (it < 15) load_tile(kfn, vbn, (((it + 1 + phase) & 15) * 64));
        // P = exp2(S'), accumulate l partials, pack to bf16 in registers
        s16x4 pk[4][2];
#pragma unroll
        for (int mik = 0; mik < 4; ++mik)
#pragma unroll
            for (int niq = 0; niq < 2; ++niq) {
                float p[4];
#pragma unroll
                for (int r = 0; r < 4; ++r) p[r] = __builtin_amdgcn_exp2f(st[mik][niq][r]);
                l_part[niq] += (p[0] + p[1]) + (p[2] + p[3]);
#pragma unroll
                for (int r = 0; r < 4; ++r) pk[mik][niq][r] = f2bs(p[r]);
            }
        // PV with current V: B-frag = concat(pk[2ki], pk[2ki+1])
#pragma unroll
        for (int ki = 0; ki < 2; ++ki)
#pragma unroll
            for (int niq = 0; niq < 2; ++niq) {
                s16x8 pb = __builtin_shufflevector(pk[2 * ki][niq], pk[2 * ki + 1][niq],
                                                   0, 1, 2, 3, 4, 5, 6, 7);
#pragma unroll
                for (int ei = 0; ei < 4; ++ei)
                    oacc[niq][ei] = mfma16(vbc[ki][ei], pb, oacc[niq][ei]);
            }
    };

    load_tile(kfA, vbA, phase * 64);
#pragma unroll
    for (int i2 = 0; i2 < 8; ++i2) {
        body(kfA, vbA, kfB, vbB, 2 * i2);
        body(kfB, vbB, kfA, vbA, 2 * i2 + 1);
    }

    // l reduction across g groups (butterfly leaves full sum in every lane)
    float li[2];
#pragma unroll
    for (int niq = 0; niq < 2; ++niq) {
        float s = l_part[niq];
        s += __shfl_xor(s, 16, 64);
        s += __shfl_xor(s, 32, 64);
        li[niq] = __builtin_amdgcn_rcpf(s);
    }
    // store O^T fragments: lane holds rows e = 16ei+4g..+3, col n = n_base+16niq+l15
    const int b = bh >> 3, h = bh & 7;
#pragma unroll
    for (int niq = 0; niq < 2; ++niq) {
        const int n = n_base + 16 * niq + l15;
#pragma unroll
        for (int ei = 0; ei < 4; ++ei) {
            s16x4 ov;
#pragma unroll
            for (int r = 0; r < 4; ++r)
                ov[r] = f2bs(fmaxf(oacc[niq][ei][r] * li[niq], 0.f));
            *(s16x4*)(Ow + ((size_t)b * 1024 + n) * 512 + h * 64 + 16 * ei + 4 * g) = ov;
        }
    }
}

// ---------------- proj GEMM: [384 x 512] x [512 x 8192] + BN -> fp32 out ----------------
// Block tile 128m x 64j (waves 2x2, per-wave 64x32); grid (3,128) = 384 blocks.
// K-loop phase-rotated per wave + register double-buffer.
__global__ __launch_bounds__(256) void k_proj(const short* __restrict__ wpb,
                                              const short* __restrict__ Ow,
                                              const float* __restrict__ s_p,
                                              const float* __restrict__ t_p,
                                              float* __restrict__ out) {
    const int t = threadIdx.x, lane = t & 63, w = t >> 6;
    const int g = lane >> 4, l15 = lane & 15;
    const int mb = blockIdx.x, jb = blockIdx.y;
    const int m_base = mb * 128 + (w >> 1) * 64;
    const int j_base = jb * 64 + (w & 1) * 32;
    const int phase = ((w + jb) & 3) * 4;  // {0,4,8,12}

    f32x4 acc[4][2];
#pragma unroll
    for (int mi = 0; mi < 4; ++mi)
#pragma unroll
        for (int ni = 0; ni < 2; ++ni) acc[mi][ni] = f32x4{0.f, 0.f, 0.f, 0.f};

    const short* Arow = wpb + (size_t)(m_base + l15) * 512 + 8 * g;
    const short* Brow = Ow + (size_t)(j_base + l15) * 512 + 8 * g;

    s16x8 aA[4], bA[2], aB[4], bB[2];
#pragma unroll
    for (int i = 0; i < 4; ++i) aA[i] = *(const s16x8*)(Arow + (size_t)i * 16 * 512 + phase * 32);
#pragma unroll
    for (int i = 0; i < 2; ++i) bA[i] = *(const s16x8*)(Brow + (size_t)i * 16 * 512 + phase * 32);

    auto pbody = [&](s16x8 (&ac)[4], s16x8 (&bc)[2], s16x8 (&an)[4], s16x8 (&bn)[2], int it) {
        if (it < 15) {
            const int ksn = (it + 1 + phase) & 15;
#pragma unroll
            for (int i = 0; i < 4; ++i)
                an[i] = *(const s16x8*)(Arow + (size_t)i * 16 * 512 + ksn * 32);
#pragma unroll
            for (int i = 0; i < 2; ++i)
                bn[i] = *(const s16x8*)(Brow + (size_t)i * 16 * 512 + ksn * 32);
        }
#pragma unroll
        for (int mi = 0; mi < 4; ++mi)
#pragma unroll
            for (int ni = 0; ni < 2; ++ni)
                acc[mi][ni] = mfma16(ac[mi], bc[ni], acc[mi][ni]);
    };
#pragma unroll
    for (int i2 = 0; i2 < 8; ++i2) {
        pbody(aA, bA, aB, bB, 2 * i2);
        pbody(aB, bB, aA, bA, 2 * i2 + 1);
    }

#pragma unroll
    for (int mi = 0; mi < 4; ++mi) {
#pragma unroll
        for (int ni = 0; ni < 2; ++ni) {
            const int j = j_base + 16 * ni + l15;
            const int bb = j >> 10, n = j & 1023;
#pragma unroll
            for (int r = 0; r < 4; ++r) {
                const int c = m_base + 16 * mi + 4 * g + r;
                float v = acc[mi][ni][r] * s_p[c] + t_p[c];
                out[((size_t)bb * 384 + c) * 1024 + n] = v;
            }
        }
    }
}

extern "C" void kernel_launch(void* const* d_in, const int* in_sizes, int n_in,
                              void* d_out, int out_size, void* d_ws, size_t ws_size,
                              hipStream_t stream) {
    const float* x  = (const float*)d_in[0];
    const float* wq = (const float*)d_in[1];
    const float* gq = (const float*)d_in[2];
    const float* bq = (const float*)d_in[3];
    const float* mq = (const float*)d_in[4];
    const float* vq = (const float*)d_in[5];
    const float* wk = (const float*)d_in[6];
    const float* gk = (const float*)d_in[7];
    const float* bk = (const float*)d_in[8];
    const float* mk = (const float*)d_in[9];
    const float* vk = (const float*)d_in[10];
    const float* wv = (const float*)d_in[11];
    const float* gv = (const float*)d_in[12];
    const float* bv = (const float*)d_in[13];
    const float* mv = (const float*)d_in[14];
    const float* vv = (const float*)d_in[15];
    const float* wp = (const float*)d_in[16];
    const float* gp = (const float*)d_in[17];
    const float* bp = (const float*)d_in[18];
    const float* mp = (const float*)d_in[19];
    const float* vp = (const float*)d_in[20];
    float* out = (float*)d_out;

    char* ws = (char*)d_ws;
    size_t off = 0;
    auto alloc = [&](size_t bytes) {
        char* p = ws + off;
        off += (bytes + 255) & ~(size_t)255;
        return p;
    };
    short* xt    = (short*)alloc((size_t)8 * 1024 * 384 * 2);
    short* wqkv  = (short*)alloc((size_t)1024 * 384 * 2);
    short* wpb   = (short*)alloc((size_t)384 * 512 * 2);
    float* s_qkv = (float*)alloc(1024 * 4);
    float* t_qkv = (float*)alloc(1024 * 4);
    float* s_p   = (float*)alloc(384 * 4);
    float* t_p   = (float*)alloc(384 * 4);
    short* Qw    = (short*)alloc((size_t)8 * 8 * 1024 * 32 * 2);
    short* Kw    = (short*)alloc((size_t)8 * 8 * 1024 * 32 * 2);
    short* Vw    = (short*)alloc((size_t)8 * 8 * 64 * 1024 * 2);
    short* Ow    = (short*)alloc((size_t)8 * 1024 * 512 * 2);
    (void)ws_size; (void)in_sizes; (void)n_in; (void)out_size;

    k_prep_x<<<dim3(12, 32, 8), 256, 0, stream>>>(x, xt);
    k_prep_w<<<dim3((1024 * 384 + 384 * 512 + 255) / 256), 256, 0, stream>>>(
        wq, wk, wv, wp, wqkv, wpb,
        gq, bq, mq, vq, gk, bk, mk, vk, gv, bv, mv, vv, gp, bp, mp, vp,
        s_qkv, t_qkv, s_p, t_p);
    k_gemm_qkv<<<dim3(8, 64), 256, 0, stream>>>(wqkv, xt, s_qkv, t_qkv, Qw, Kw, Vw);
    k_attn<<<dim3(512), 256, 0, stream>>>(Qw, Kw, Vw, Ow);
    k_proj<<<dim3(3, 128), 256, 0, stream>>>(wpb, Ow, s_p, t_p, out);
}

// Round 8
// 76.509 us; speedup vs baseline: 2.7412x; 2.7412x over previous
//
#include <hip/hip_runtime.h>
#include <hip/hip_bf16.h>

#define DEVI __device__ __forceinline__

typedef __attribute__((ext_vector_type(8))) short s16x8;
typedef __attribute__((ext_vector_type(4))) short s16x4;
typedef __attribute__((ext_vector_type(4))) float f32x4;

// ---- problem constants ----
// x: (8, 384, 32, 32); heads=8, dk=32, dv=64; N=1024 tokens; Cqk=256, Cv=512
#define LOG2E 1.4426950408889634f

DEVI short f2bs(float f) {  // fp32 -> bf16 bits (RNE)
    unsigned u = __builtin_bit_cast(unsigned, f);
    unsigned r = (u + 0x7fffu + ((u >> 16) & 1u)) >> 16;
    return (short)r;
}

DEVI f32x4 mfma16(s16x8 a, s16x8 b, f32x4 c) {
    return __builtin_amdgcn_mfma_f32_16x16x32_bf16(a, b, c, 0, 0, 0);
}

// ---------------- prep: x (b,c,n) fp32 -> xt (b,n,c) bf16 ----------------
__global__ __launch_bounds__(256) void k_prep_x(const float* __restrict__ x,
                                                short* __restrict__ xt) {
    __shared__ float tile[32][33];
    const int ct = blockIdx.x, nt = blockIdx.y, b = blockIdx.z;
    const int t = threadIdx.x;
    {
        const int j = t & 31, i0 = (t >> 5) * 4;
        const float* src = x + ((size_t)b * 384 + (size_t)ct * 32) * 1024 + nt * 32;
#pragma unroll
        for (int ii = 0; ii < 4; ++ii)
            tile[i0 + ii][j] = src[(size_t)(i0 + ii) * 1024 + j];
    }
    __syncthreads();
    {
        const int ii = t & 31, j0 = (t >> 5) * 4;
        short* dst = xt + ((size_t)b * 1024 + (size_t)nt * 32) * 384 + ct * 32;
#pragma unroll
        for (int jj = 0; jj < 4; ++jj)
            dst[(size_t)(j0 + jj) * 384 + ii] = f2bs(tile[ii][j0 + jj]);
    }
}

// ---------------- prep: weights fp32 -> bf16, plus BN fold ----------------
__global__ __launch_bounds__(256) void k_prep_w(
    const float* __restrict__ wq, const float* __restrict__ wk,
    const float* __restrict__ wv, const float* __restrict__ wp,
    short* __restrict__ wqkv, short* __restrict__ wpb,
    const float* gq, const float* bq, const float* mq, const float* vq,
    const float* gk, const float* bk, const float* mk, const float* vk,
    const float* gv, const float* bv, const float* mv, const float* vv,
    const float* gp, const float* bp, const float* mp, const float* vp,
    float* s_qkv, float* t_qkv, float* s_p, float* t_p) {
    int i = blockIdx.x * 256 + threadIdx.x;
    if (i < 1024) {
        const float *g, *bb, *mm, *vv_;
        int o = i;
        float post = 1.0f;
        if (i < 256)      { g = gq; bb = bq; mm = mq; vv_ = vq; post = LOG2E; }
        else if (i < 512) { g = gk; bb = bk; mm = mk; vv_ = vk; o = i - 256; }
        else              { g = gv; bb = bv; mm = mv; vv_ = vv; o = i - 512; }
        float s = g[o] * rsqrtf(vv_[o] + 1e-5f);
        s_qkv[i] = s * post;
        t_qkv[i] = (bb[o] - mm[o] * s) * post;
        if (i < 384) {
            float sp = gp[i] * rsqrtf(vp[i] + 1e-5f);
            s_p[i] = sp;
            t_p[i] = bp[i] - mp[i] * sp;
        }
    }
    const int NQKV = 1024 * 384;
    if (i < NQKV) {
        int o = i / 384;
        float v;
        if (o < 256)      v = wq[i];
        else if (o < 512) v = wk[i - 256 * 384];
        else              v = wv[i - 512 * 384];
        wqkv[i] = f2bs(v);
    } else {
        int j = i - NQKV;
        if (j < 384 * 512) wpb[j] = f2bs(wp[j]);
    }
}

// ---------------- QKV GEMM: LDS-staged 128x128 tile, BK=32 ----------------
// A = wqkv [1024 x 384], B = xt [8192 x 384] (both K-contiguous).
// LDS layout per tile: [rows][32 shorts], 16B unit u at row*32+u*8 holds global
// k-slot (u ^ (row&3)) -> fragment read at 8*(g^(row&3)) returns k=8g (swizzle-free banks).
__global__ __launch_bounds__(256, 2) void k_gemm_qkv(
    const short* __restrict__ wqkv, const short* __restrict__ xt,
    const float* __restrict__ s_qkv, const float* __restrict__ t_qkv,
    short* __restrict__ Qw, short* __restrict__ Kw, short* __restrict__ Vw) {
    __shared__ short AB[2][8192];  // A 4096 shorts + B 4096 shorts per buffer
    const int t = threadIdx.x, lane = t & 63, w = t >> 6;
    const int g = lane >> 4, l15 = lane & 15;
    const int wr = w >> 1, wc = w & 1;
    const int mb = blockIdx.x, jb = blockIdx.y;

    // stage source pointers (chunks t, t+256 for A and B)
    const int cr = t >> 2, cu = t & 3;            // row 0..63, unit 0..3
    const int cperm = 8 * (cu ^ (cr & 3));
    const short* gA0 = wqkv + (size_t)(mb * 128 + cr) * 384 + cperm;
    const short* gA1 = wqkv + (size_t)(mb * 128 + cr + 64) * 384 + cperm;
    const short* gB0 = xt + (size_t)((size_t)jb * 128 + cr) * 384 + cperm;
    const short* gB1 = xt + (size_t)((size_t)jb * 128 + cr + 64) * 384 + cperm;

    f32x4 acc[4][4];
#pragma unroll
    for (int mi = 0; mi < 4; ++mi)
#pragma unroll
        for (int ni = 0; ni < 4; ++ni) acc[mi][ni] = f32x4{0.f, 0.f, 0.f, 0.f};

    const int kcol = 8 * (g ^ (l15 & 3));

    s16x8 rA0, rA1, rB0, rB1;
    auto stage_load = [&](int ks) {
        rA0 = *(const s16x8*)(gA0 + ks * 32);
        rA1 = *(const s16x8*)(gA1 + ks * 32);
        rB0 = *(const s16x8*)(gB0 + ks * 32);
        rB1 = *(const s16x8*)(gB1 + ks * 32);
    };
    auto stage_write = [&](int buf) {
        short* base = AB[buf];
        *(s16x8*)(base + t * 8) = rA0;
        *(s16x8*)(base + (t + 256) * 8) = rA1;
        *(s16x8*)(base + 4096 + t * 8) = rB0;
        *(s16x8*)(base + 4096 + (t + 256) * 8) = rB1;
    };

    stage_load(0);
    stage_write(0);
    __syncthreads();

    for (int ks = 0; ks < 12; ++ks) {
        if (ks < 11) stage_load(ks + 1);
        const short* base = AB[ks & 1];
        s16x8 a[4], b[4];
#pragma unroll
        for (int mi = 0; mi < 4; ++mi)
            a[mi] = *(const s16x8*)(base + (64 * wr + 16 * mi + l15) * 32 + kcol);
#pragma unroll
        for (int ni = 0; ni < 4; ++ni)
            b[ni] = *(const s16x8*)(base + 4096 + (64 * wc + 16 * ni + l15) * 32 + kcol);
#pragma unroll
        for (int mi = 0; mi < 4; ++mi)
#pragma unroll
            for (int ni = 0; ni < 4; ++ni)
                acc[mi][ni] = mfma16(a[mi], b[ni], acc[mi][ni]);
        if (ks < 11) stage_write((ks + 1) & 1);
        __syncthreads();
    }

    const int m_base = mb * 128 + 64 * wr;
    const int j_base = jb * 128 + 64 * wc;
#pragma unroll
    for (int mi = 0; mi < 4; ++mi) {
        const int o0 = m_base + 16 * mi;
#pragma unroll
        for (int ni = 0; ni < 4; ++ni) {
            const int j = j_base + 16 * ni + l15;
            const int bb = j >> 10, n = j & 1023;
#pragma unroll
            for (int r = 0; r < 4; ++r) {
                const int o = o0 + 4 * g + r;
                float val = acc[mi][ni][r] * s_qkv[o] + t_qkv[o];
                short bv = f2bs(val);
                if (o0 < 256) {
                    int h = o >> 5, d = o & 31;
                    Qw[(((size_t)bb * 8 + h) * 1024 + n) * 32 + d] = bv;
                } else if (o0 < 512) {
                    int o2 = o - 256;
                    int h = o2 >> 5, d = o2 & 31;
                    Kw[(((size_t)bb * 8 + h) * 1024 + n) * 32 + d] = bv;
                } else {
                    int o2 = o - 512;
                    int h = o2 >> 6, e = o2 & 63;
                    Vw[(((size_t)bb * 8 + h) * 64 + e) * 1024 + n] = bv;
                }
            }
        }
    }
}

// ---------------- attention per (b,h): LDS-staged K/V, register P ----------------
// 4 waves/block share one bh: stage K tile (64x32 shorts) + V tile (64 e-rows x 64 m)
// cooperatively per iteration (coalesced), double-buffered, 1 barrier/iter.
// Permuted-K trick (R6): S^T D-layout == PV B-layout, P stays in registers.
__global__ __launch_bounds__(256, 2) void k_attn(const short* __restrict__ Qw,
                                                 const short* __restrict__ Kw,
                                                 const short* __restrict__ Vw,
                                                 short* __restrict__ Ow) {
    __shared__ short KV[2][6144];  // K 2048 shorts + V 4096 shorts per buffer
    const int t = threadIdx.x, lane = t & 63, w = t >> 6;
    const int g = lane >> 4, l15 = lane & 15;
    // blockIdx.x = (bh&7) + 8*(rb + 8*(bh>>3)) => all 8 rb of one bh on one XCD
    const int low3 = blockIdx.x & 7;
    const int mid = blockIdx.x >> 3;
    const int rb = mid & 7;
    const int bh = ((mid >> 3) << 3) | low3;
    const int n_base = rb * 128 + w * 32;
    const short* Qb = Qw + (size_t)bh * (1024 * 32);
    const short* Kb = Kw + (size_t)bh * (1024 * 32);
    const short* Vb = Vw + (size_t)bh * (64 * 1024);

    s16x8 qf[2];
#pragma unroll
    for (int i = 0; i < 2; ++i)
        qf[i] = *(const s16x8*)(Qb + (size_t)(n_base + 16 * i + l15) * 32 + 8 * g);

    // stage source pointers: K chunk t (row t>>2, unit t&3), V chunks t and t+256
    const int skr = t >> 2, sku = t & 3;
    const short* gK = Kb + (size_t)skr * 32 + 8 * (sku ^ (skr & 3));
    const int v0r = t >> 3, vu = t & 7;
    const short* gV0 = Vb + (size_t)v0r * 1024 + 8 * (vu ^ (v0r & 7));
    const short* gV1 = Vb + (size_t)(v0r + 32) * 1024 + 8 * (vu ^ ((v0r + 32) & 7));

    f32x4 oacc[2][4];
#pragma unroll
    for (int niq = 0; niq < 2; ++niq)
#pragma unroll
        for (int ei = 0; ei < 4; ++ei) oacc[niq][ei] = f32x4{0.f, 0.f, 0.f, 0.f};
    float l_part[2] = {0.f, 0.f};

    // fragment read offsets
    const int krow = 8 * (l15 >> 2) + (l15 & 3);
    const int kcol = 8 * (g ^ (l15 & 3));

    s16x8 rk, rv0, rv1;
    auto stage_load = [&](int m0) {
        rk = *(const s16x8*)(gK + m0 * 32);
        rv0 = *(const s16x8*)(gV0 + m0);
        rv1 = *(const s16x8*)(gV1 + m0);
    };
    auto stage_write = [&](int buf) {
        short* base = KV[buf];
        *(s16x8*)(base + t * 8) = rk;
        *(s16x8*)(base + 2048 + t * 8) = rv0;
        *(s16x8*)(base + 2048 + (t + 256) * 8) = rv1;
    };

    stage_load(0);
    stage_write(0);
    __syncthreads();

    for (int mt = 0; mt < 16; ++mt) {
        if (mt < 15) stage_load((mt + 1) * 64);
        const short* base = KV[mt & 1];
        // K fragments (permuted rows {0,4,32,36})
        s16x8 kf[4];
        kf[0] = *(const s16x8*)(base + (krow + 0) * 32 + kcol);
        kf[1] = *(const s16x8*)(base + (krow + 4) * 32 + kcol);
        kf[2] = *(const s16x8*)(base + (krow + 32) * 32 + kcol);
        kf[3] = *(const s16x8*)(base + (krow + 36) * 32 + kcol);
        // V fragments
        s16x8 vb[2][4];
#pragma unroll
        for (int ki = 0; ki < 2; ++ki)
#pragma unroll
            for (int ei = 0; ei < 4; ++ei) {
                const int row = 16 * ei + l15;
                vb[ki][ei] = *(const s16x8*)(base + 2048 + row * 64 +
                                             8 * ((4 * ki + g) ^ (row & 7)));
            }
        // S^T: st[mik][niq][r] = S[m0 + 8g + r + {0,4,32,36}[mik]][n_base+16niq+l15]
        f32x4 st[4][2];
#pragma unroll
        for (int mik = 0; mik < 4; ++mik)
#pragma unroll
            for (int niq = 0; niq < 2; ++niq)
                st[mik][niq] = mfma16(kf[mik], qf[niq], f32x4{0.f, 0.f, 0.f, 0.f});
        // P = exp2(S'), accumulate l partials, pack to bf16 in registers
        s16x4 pk[4][2];
#pragma unroll
        for (int mik = 0; mik < 4; ++mik)
#pragma unroll
            for (int niq = 0; niq < 2; ++niq) {
                float p[4];
#pragma unroll
                for (int r = 0; r < 4; ++r) p[r] = __builtin_amdgcn_exp2f(st[mik][niq][r]);
                l_part[niq] += (p[0] + p[1]) + (p[2] + p[3]);
#pragma unroll
                for (int r = 0; r < 4; ++r) pk[mik][niq][r] = f2bs(p[r]);
            }
        // PV: B-frag = concat(pk[2ki], pk[2ki+1]) -- k-slots line up by construction
#pragma unroll
        for (int ki = 0; ki < 2; ++ki)
#pragma unroll
            for (int niq = 0; niq < 2; ++niq) {
                s16x8 pb = __builtin_shufflevector(pk[2 * ki][niq], pk[2 * ki + 1][niq],
                                                   0, 1, 2, 3, 4, 5, 6, 7);
#pragma unroll
                for (int ei = 0; ei < 4; ++ei)
                    oacc[niq][ei] = mfma16(vb[ki][ei], pb, oacc[niq][ei]);
            }
        if (mt < 15) stage_write((mt + 1) & 1);
        __syncthreads();
    }

    // l reduction across g groups (butterfly leaves full sum in every lane)
    float li[2];
#pragma unroll
    for (int niq = 0; niq < 2; ++niq) {
        float s = l_part[niq];
        s += __shfl_xor(s, 16, 64);
        s += __shfl_xor(s, 32, 64);
        li[niq] = __builtin_amdgcn_rcpf(s);
    }
    // store O^T fragments: lane holds rows e = 16ei+4g..+3, col n = n_base+16niq+l15
    const int b = bh >> 3, h = bh & 7;
#pragma unroll
    for (int niq = 0; niq < 2; ++niq) {
        const int n = n_base + 16 * niq + l15;
#pragma unroll
        for (int ei = 0; ei < 4; ++ei) {
            s16x4 ov;
#pragma unroll
            for (int r = 0; r < 4; ++r)
                ov[r] = f2bs(fmaxf(oacc[niq][ei][r] * li[niq], 0.f));
            *(s16x4*)(Ow + ((size_t)b * 1024 + n) * 512 + h * 64 + 16 * ei + 4 * g) = ov;
        }
    }
}

// ---------------- proj GEMM: LDS-staged 64x64 tile, BK=32 ----------------
// A = wpb [384 x 512], B = Ow [8192 x 512]; grid (6,128)=768 blocks.
__global__ __launch_bounds__(256, 3) void k_proj(const short* __restrict__ wpb,
                                                 const short* __restrict__ Ow,
                                                 const float* __restrict__ s_p,
                                                 const float* __restrict__ t_p,
                                                 float* __restrict__ out) {
    __shared__ short AB[2][4096];  // A 2048 shorts + B 2048 shorts per buffer
    const int t = threadIdx.x, lane = t & 63, w = t >> 6;
    const int g = lane >> 4, l15 = lane & 15;
    const int wr = w >> 1, wc = w & 1;
    const int mb = blockIdx.x, jb = blockIdx.y;

    const int cr = t >> 2, cu = t & 3;
    const int cperm = 8 * (cu ^ (cr & 3));
    const short* gA = wpb + (size_t)(mb * 64 + cr) * 512 + cperm;
    const short* gB = Ow + (size_t)((size_t)jb * 64 + cr) * 512 + cperm;

    f32x4 acc[2][2];
#pragma unroll
    for (int mi = 0; mi < 2; ++mi)
#pragma unroll
        for (int ni = 0; ni < 2; ++ni) acc[mi][ni] = f32x4{0.f, 0.f, 0.f, 0.f};

    const int kcol = 8 * (g ^ (l15 & 3));

    s16x8 rA, rB;
    auto stage_load = [&](int ks) {
        rA = *(const s16x8*)(gA + ks * 32);
        rB = *(const s16x8*)(gB + ks * 32);
    };
    auto stage_write = [&](int buf) {
        short* base = AB[buf];
        *(s16x8*)(base + t * 8) = rA;
        *(s16x8*)(base + 2048 + t * 8) = rB;
    };

    stage_load(0);
    stage_write(0);
    __syncthreads();

    for (int ks = 0; ks < 16; ++ks) {
        if (ks < 15) stage_load(ks + 1);
        const short* base = AB[ks & 1];
        s16x8 a[2], b[2];
#pragma unroll
        for (int mi = 0; mi < 2; ++mi)
            a[mi] = *(const s16x8*)(base + (32 * wr + 16 * mi + l15) * 32 + kcol);
#pragma unroll
        for (int ni = 0; ni < 2; ++ni)
            b[ni] = *(const s16x8*)(base + 2048 + (32 * wc + 16 * ni + l15) * 32 + kcol);
#pragma unroll
        for (int mi = 0; mi < 2; ++mi)
#pragma unroll
            for (int ni = 0; ni < 2; ++ni)
                acc[mi][ni] = mfma16(a[mi], b[ni], acc[mi][ni]);
        if (ks < 15) stage_write((ks + 1) & 1);
        __syncthreads();
    }

    const int m_base = mb * 64 + 32 * wr;
    const int j_base = jb * 64 + 32 * wc;
#pragma unroll
    for (int mi = 0; mi < 2; ++mi) {
#pragma unroll
        for (int ni = 0; ni < 2; ++ni) {
            const int j = j_base + 16 * ni + l15;
            const int bb = j >> 10, n = j & 1023;
#pragma unroll
            for (int r = 0; r < 4; ++r) {
                const int c = m_base + 16 * mi + 4 * g + r;
                float v = acc[mi][ni][r] * s_p[c] + t_p[c];
                out[((size_t)bb * 384 + c) * 1024 + n] = v;
            }
        }
    }
}

extern "C" void kernel_launch(void* const* d_in, const int* in_sizes, int n_in,
                              void* d_out, int out_size, void* d_ws, size_t ws_size,
                              hipStream_t stream) {
    const float* x  = (const float*)d_in[0];
    const float* wq = (const float*)d_in[1];
    const float* gq = (const float*)d_in[2];
    const float* bq = (const float*)d_in[3];
    const float* mq = (const float*)d_in[4];
    const float* vq = (const float*)d_in[5];
    const float* wk = (const float*)d_in[6];
    const float* gk = (const float*)d_in[7];
    const float* bk = (const float*)d_in[8];
    const float* mk = (const float*)d_in[9];
    const float* vk = (const float*)d_in[10];
    const float* wv = (const float*)d_in[11];
    const float* gv = (const float*)d_in[12];
    const float* bv = (const float*)d_in[13];
    const float* mv = (const float*)d_in[14];
    const float* vv = (const float*)d_in[15];
    const float* wp = (const float*)d_in[16];
    const float* gp = (const float*)d_in[17];
    const float* bp = (const float*)d_in[18];
    const float* mp = (const float*)d_in[19];
    const float* vp = (const float*)d_in[20];
    float* out = (float*)d_out;

    char* ws = (char*)d_ws;
    size_t off = 0;
    auto alloc = [&](size_t bytes) {
        char* p = ws + off;
        off += (bytes + 255) & ~(size_t)255;
        return p;
    };
    short* xt    = (short*)alloc((size_t)8 * 1024 * 384 * 2);
    short* wqkv  = (short*)alloc((size_t)1024 * 384 * 2);
    short* wpb   = (short*)alloc((size_t)384 * 512 * 2);
    float* s_qkv = (float*)alloc(1024 * 4);
    float* t_qkv = (float*)alloc(1024 * 4);
    float* s_p   = (float*)alloc(384 * 4);
    float* t_p   = (float*)alloc(384 * 4);
    short* Qw    = (short*)alloc((size_t)8 * 8 * 1024 * 32 * 2);
    short* Kw    = (short*)alloc((size_t)8 * 8 * 1024 * 32 * 2);
    short* Vw    = (short*)alloc((size_t)8 * 8 * 64 * 1024 * 2);
    short* Ow    = (short*)alloc((size_t)8 * 1024 * 512 * 2);
    (void)ws_size; (void)in_sizes; (void)n_in; (void)out_size;

    k_prep_x<<<dim3(12, 32, 8), 256, 0, stream>>>(x, xt);
    k_prep_w<<<dim3((1024 * 384 + 384 * 512 + 255) / 256), 256, 0, stream>>>(
        wq, wk, wv, wp, wqkv, wpb,
        gq, bq, mq, vq, gk, bk, mk, vk, gv, bv, mv, vv, gp, bp, mp, vp,
        s_qkv, t_qkv, s_p, t_p);
    k_gemm_qkv<<<dim3(8, 64), 256, 0, stream>>>(wqkv, xt, s_qkv, t_qkv, Qw, Kw, Vw);
    k_attn<<<dim3(512), 256, 0, stream>>>(Qw, Kw, Vw, Ow);
    k_proj<<<dim3(6, 128), 256, 0, stream>>>(wpb, Ow, s_p, t_p, out);
}

// Round 10
// 58.802 us; speedup vs baseline: 3.5666x; 1.3011x over previous
//
#include <hip/hip_runtime.h>
#include <hip/hip_bf16.h>

#define DEVI __device__ __forceinline__

typedef __attribute__((ext_vector_type(8))) short s16x8;
typedef __attribute__((ext_vector_type(4))) short s16x4;
typedef __attribute__((ext_vector_type(4))) float f32x4;

// ---- problem constants ----
// x: (8, 384, 32, 32); heads=8, dk=32, dv=64; N=1024 tokens; Cqk=256, Cv=512
#define LOG2E 1.4426950408889634f

DEVI short f2bs(float f) {  // fp32 -> bf16 bits (RNE)
    unsigned u = __builtin_bit_cast(unsigned, f);
    unsigned r = (u + 0x7fffu + ((u >> 16) & 1u)) >> 16;
    return (short)r;
}

DEVI f32x4 mfma16(s16x8 a, s16x8 b, f32x4 c) {
    return __builtin_amdgcn_mfma_f32_16x16x32_bf16(a, b, c, 0, 0, 0);
}

// async global->LDS 16B copy; LDS side is linear in lane order, swizzle is in gsrc
DEVI void gl_lds16(const short* g, short* l) {
    __builtin_amdgcn_global_load_lds(
        (const __attribute__((address_space(1))) unsigned*)(const void*)g,
        (__attribute__((address_space(3))) unsigned*)(void*)l, 16, 0, 0);
}

// ---------------- prep: x (b,c,n) fp32 -> xt (b,n,c) bf16 ----------------
__global__ __launch_bounds__(256) void k_prep_x(const float* __restrict__ x,
                                                short* __restrict__ xt) {
    __shared__ float tile[32][33];
    const int ct = blockIdx.x, nt = blockIdx.y, b = blockIdx.z;
    const int t = threadIdx.x;
    {
        const int j = t & 31, i0 = (t >> 5) * 4;
        const float* src = x + ((size_t)b * 384 + (size_t)ct * 32) * 1024 + nt * 32;
#pragma unroll
        for (int ii = 0; ii < 4; ++ii)
            tile[i0 + ii][j] = src[(size_t)(i0 + ii) * 1024 + j];
    }
    __syncthreads();
    {
        const int ii = t & 31, j0 = (t >> 5) * 4;
        short* dst = xt + ((size_t)b * 1024 + (size_t)nt * 32) * 384 + ct * 32;
#pragma unroll
        for (int jj = 0; jj < 4; ++jj)
            dst[(size_t)(j0 + jj) * 384 + ii] = f2bs(tile[ii][j0 + jj]);
    }
}

// ---------------- prep: weights fp32 -> bf16, plus BN fold ----------------
__global__ __launch_bounds__(256) void k_prep_w(
    const float* __restrict__ wq, const float* __restrict__ wk,
    const float* __restrict__ wv, const float* __restrict__ wp,
    short* __restrict__ wqkv, short* __restrict__ wpb,
    const float* gq, const float* bq, const float* mq, const float* vq,
    const float* gk, const float* bk, const float* mk, const float* vk,
    const float* gv, const float* bv, const float* mv, const float* vv,
    const float* gp, const float* bp, const float* mp, const float* vp,
    float* s_qkv, float* t_qkv, float* s_p, float* t_p) {
    int i = blockIdx.x * 256 + threadIdx.x;
    if (i < 1024) {
        const float *g, *bb, *mm, *vv_;
        int o = i;
        float post = 1.0f;
        if (i < 256)      { g = gq; bb = bq; mm = mq; vv_ = vq; post = LOG2E; }
        else if (i < 512) { g = gk; bb = bk; mm = mk; vv_ = vk; o = i - 256; }
        else              { g = gv; bb = bv; mm = mv; vv_ = vv; o = i - 512; }
        float s = g[o] * rsqrtf(vv_[o] + 1e-5f);
        s_qkv[i] = s * post;
        t_qkv[i] = (bb[o] - mm[o] * s) * post;
        if (i < 384) {
            float sp = gp[i] * rsqrtf(vp[i] + 1e-5f);
            s_p[i] = sp;
            t_p[i] = bp[i] - mp[i] * sp;
        }
    }
    const int NQKV = 1024 * 384;
    if (i < NQKV) {
        int o = i / 384;
        float v;
        if (o < 256)      v = wq[i];
        else if (o < 512) v = wk[i - 256 * 384];
        else              v = wv[i - 512 * 384];
        wqkv[i] = f2bs(v);
    } else {
        int j = i - NQKV;
        if (j < 384 * 512) wpb[j] = f2bs(wp[j]);
    }
}

// ---------------- QKV GEMM: LDS-staged 128x128 tile, BK=32, global_load_lds ----------------
// grid (jb=64, mb=8): blocks sharing the B(x)-tile land on one XCD (bid%8 == jb%8).
__global__ __launch_bounds__(256, 2) void k_gemm_qkv(
    const short* __restrict__ wqkv, const short* __restrict__ xt,
    const float* __restrict__ s_qkv, const float* __restrict__ t_qkv,
    short* __restrict__ Qw, short* __restrict__ Kw, short* __restrict__ Vw) {
    __shared__ short AB[2][8192];  // A 4096 shorts + B 4096 shorts per buffer
    const int t = threadIdx.x, lane = t & 63, w = t >> 6;
    const int g = lane >> 4, l15 = lane & 15;
    const int wr = w >> 1, wc = w & 1;
    const int jb = blockIdx.x, mb = blockIdx.y;

    // stage source pointers (chunk row cr, 16B unit cu, k-unit permuted by row&3)
    const int cr = t >> 2, cu = t & 3;
    const int cperm = 8 * (cu ^ (cr & 3));
    const short* gA0 = wqkv + (size_t)(mb * 128 + cr) * 384 + cperm;
    const short* gA1 = wqkv + (size_t)(mb * 128 + cr + 64) * 384 + cperm;
    const short* gB0 = xt + (size_t)((size_t)jb * 128 + cr) * 384 + cperm;
    const short* gB1 = xt + (size_t)((size_t)jb * 128 + cr + 64) * 384 + cperm;

    f32x4 acc[4][4];
#pragma unroll
    for (int mi = 0; mi < 4; ++mi)
#pragma unroll
        for (int ni = 0; ni < 4; ++ni) acc[mi][ni] = f32x4{0.f, 0.f, 0.f, 0.f};

    const int kcol = 8 * (g ^ (l15 & 3));

    auto stage = [&](int ks, int buf) {
        short* base = AB[buf];
        gl_lds16(gA0 + ks * 32, base + t * 8);
        gl_lds16(gA1 + ks * 32, base + (t + 256) * 8);
        gl_lds16(gB0 + ks * 32, base + 4096 + t * 8);
        gl_lds16(gB1 + ks * 32, base + 4096 + (t + 256) * 8);
    };

    stage(0, 0);
    __syncthreads();

    for (int ks = 0; ks < 12; ++ks) {
        if (ks < 11) stage(ks + 1, (ks + 1) & 1);
        const short* base = AB[ks & 1];
        s16x8 a[4], b[4];
#pragma unroll
        for (int mi = 0; mi < 4; ++mi)
            a[mi] = *(const s16x8*)(base + (64 * wr + 16 * mi + l15) * 32 + kcol);
#pragma unroll
        for (int ni = 0; ni < 4; ++ni)
            b[ni] = *(const s16x8*)(base + 4096 + (64 * wc + 16 * ni + l15) * 32 + kcol);
#pragma unroll
        for (int mi = 0; mi < 4; ++mi)
#pragma unroll
            for (int ni = 0; ni < 4; ++ni)
                acc[mi][ni] = mfma16(a[mi], b[ni], acc[mi][ni]);
        __syncthreads();
    }

    const int m_base = mb * 128 + 64 * wr;
    const int j_base = jb * 128 + 64 * wc;
#pragma unroll
    for (int mi = 0; mi < 4; ++mi) {
        const int o0 = m_base + 16 * mi;
#pragma unroll
        for (int ni = 0; ni < 4; ++ni) {
            const int j = j_base + 16 * ni + l15;
            const int bb = j >> 10, n = j & 1023;
            if (o0 < 512) {
                // Q/K: d = o&31 consecutive over r -> vector store
                const int o = o0 + 4 * g;
                const int isK = o0 >= 256;
                const int o2 = o - (isK ? 256 : 0);
                const int h = o2 >> 5, d0 = o2 & 31;
                s16x4 ov;
#pragma unroll
                for (int r = 0; r < 4; ++r)
                    ov[r] = f2bs(acc[mi][ni][r] * s_qkv[o + r] + t_qkv[o + r]);
                short* dst = (isK ? Kw : Qw) + (((size_t)bb * 8 + h) * 1024 + n) * 32 + d0;
                *(s16x4*)dst = ov;
            } else {
#pragma unroll
                for (int r = 0; r < 4; ++r) {
                    const int o = o0 + 4 * g + r;
                    float val = acc[mi][ni][r] * s_qkv[o] + t_qkv[o];
                    const int o2 = o - 512;
                    const int h = o2 >> 6, e = o2 & 63;
                    Vw[(((size_t)bb * 8 + h) * 64 + e) * 1024 + n] = f2bs(val);
                }
            }
        }
    }
}

// ---------------- attention per (b,h): LDS-staged K/V via global_load_lds ----------------
// 4 waves/block share one bh; K tile 4KB + V tile 8KB double-buffered, 1 barrier/iter.
// Permuted-K trick: S^T D-layout == PV B-layout, P stays in registers.
__global__ __launch_bounds__(256, 2) void k_attn(const short* __restrict__ Qw,
                                                 const short* __restrict__ Kw,
                                                 const short* __restrict__ Vw,
                                                 short* __restrict__ Ow) {
    __shared__ short KV[2][6144];  // K 2048 shorts + V 4096 shorts per buffer
    const int t = threadIdx.x, lane = t & 63, w = t >> 6;
    const int g = lane >> 4, l15 = lane & 15;
    // blockIdx.x = (bh&7) + 8*(rb + 8*(bh>>3)) => all 8 rb of one bh on one XCD
    const int low3 = blockIdx.x & 7;
    const int mid = blockIdx.x >> 3;
    const int rb = mid & 7;
    const int bh = ((mid >> 3) << 3) | low3;
    const int n_base = rb * 128 + w * 32;
    const short* Qb = Qw + (size_t)bh * (1024 * 32);
    const short* Kb = Kw + (size_t)bh * (1024 * 32);
    const short* Vb = Vw + (size_t)bh * (64 * 1024);

    s16x8 qf[2];
#pragma unroll
    for (int i = 0; i < 2; ++i)
        qf[i] = *(const s16x8*)(Qb + (size_t)(n_base + 16 * i + l15) * 32 + 8 * g);

    // stage source pointers: K chunk (row t>>2, unit t&3 permuted), V chunks t, t+256
    const int skr = t >> 2, sku = t & 3;
    const short* gK = Kb + (size_t)skr * 32 + 8 * (sku ^ (skr & 3));
    const int v0r = t >> 3, vu = t & 7;
    const short* gV0 = Vb + (size_t)v0r * 1024 + 8 * (vu ^ (v0r & 7));
    const short* gV1 = Vb + (size_t)(v0r + 32) * 1024 + 8 * (vu ^ ((v0r + 32) & 7));

    f32x4 oacc[2][4];
#pragma unroll
    for (int niq = 0; niq < 2; ++niq)
#pragma unroll
        for (int ei = 0; ei < 4; ++ei) oacc[niq][ei] = f32x4{0.f, 0.f, 0.f, 0.f};
    float l_part[2] = {0.f, 0.f};

    // fragment read offsets
    const int krow = 8 * (l15 >> 2) + (l15 & 3);
    const int kcol = 8 * (g ^ (l15 & 3));

    auto stage = [&](int m0, int buf) {
        short* base = KV[buf];
        gl_lds16(gK + m0 * 32, base + t * 8);
        gl_lds16(gV0 + m0, base + 2048 + t * 8);
        gl_lds16(gV1 + m0, base + 2048 + (t + 256) * 8);
    };

    stage(0, 0);
    __syncthreads();

    for (int mt = 0; mt < 16; ++mt) {
        if (mt < 15) stage((mt + 1) * 64, (mt + 1) & 1);
        const short* base = KV[mt & 1];
        // K fragments (permuted rows {0,4,32,36})
        s16x8 kf[4];
        kf[0] = *(const s16x8*)(base + (krow + 0) * 32 + kcol);
        kf[1] = *(const s16x8*)(base + (krow + 4) * 32 + kcol);
        kf[2] = *(const s16x8*)(base + (krow + 32) * 32 + kcol);
        kf[3] = *(const s16x8*)(base + (krow + 36) * 32 + kcol);
        // V fragments
        s16x8 vb[2][4];
#pragma unroll
        for (int ki = 0; ki < 2; ++ki)
#pragma unroll
            for (int ei = 0; ei < 4; ++ei) {
                const int row = 16 * ei + l15;
                vb[ki][ei] = *(const s16x8*)(base + 2048 + row * 64 +
                                             8 * ((4 * ki + g) ^ (row & 7)));
            }
        // S^T: st[mik][niq][r] = S[m0 + 8g + r + {0,4,32,36}[mik]][n_base+16niq+l15]
        f32x4 st[4][2];
#pragma unroll
        for (int mik = 0; mik < 4; ++mik)
#pragma unroll
            for (int niq = 0; niq < 2; ++niq)
                st[mik][niq] = mfma16(kf[mik], qf[niq], f32x4{0.f, 0.f, 0.f, 0.f});
        // P = exp2(S'), accumulate l partials, pack to bf16 in registers
        s16x4 pk[4][2];
#pragma unroll
        for (int mik = 0; mik < 4; ++mik)
#pragma unroll
            for (int niq = 0; niq < 2; ++niq) {
                float p[4];
#pragma unroll
                for (int r = 0; r < 4; ++r) p[r] = __builtin_amdgcn_exp2f(st[mik][niq][r]);
                l_part[niq] += (p[0] + p[1]) + (p[2] + p[3]);
#pragma unroll
                for (int r = 0; r < 4; ++r) pk[mik][niq][r] = f2bs(p[r]);
            }
        // PV: B-frag = concat(pk[2ki], pk[2ki+1]) -- k-slots line up by construction
#pragma unroll
        for (int ki = 0; ki < 2; ++ki)
#pragma unroll
            for (int niq = 0; niq < 2; ++niq) {
                s16x8 pb = __builtin_shufflevector(pk[2 * ki][niq], pk[2 * ki + 1][niq],
                                                   0, 1, 2, 3, 4, 5, 6, 7);
#pragma unroll
                for (int ei = 0; ei < 4; ++ei)
                    oacc[niq][ei] = mfma16(vb[ki][ei], pb, oacc[niq][ei]);
            }
        __syncthreads();
    }

    // l reduction across g groups (butterfly leaves full sum in every lane)
    float li[2];
#pragma unroll
    for (int niq = 0; niq < 2; ++niq) {
        float s = l_part[niq];
        s += __shfl_xor(s, 16, 64);
        s += __shfl_xor(s, 32, 64);
        li[niq] = __builtin_amdgcn_rcpf(s);
    }
    // store O^T fragments: lane holds rows e = 16ei+4g..+3, col n = n_base+16niq+l15
    const int b = bh >> 3, h = bh & 7;
#pragma unroll
    for (int niq = 0; niq < 2; ++niq) {
        const int n = n_base + 16 * niq + l15;
#pragma unroll
        for (int ei = 0; ei < 4; ++ei) {
            s16x4 ov;
#pragma unroll
            for (int r = 0; r < 4; ++r)
                ov[r] = f2bs(fmaxf(oacc[niq][ei][r] * li[niq], 0.f));
            *(s16x4*)(Ow + ((size_t)b * 1024 + n) * 512 + h * 64 + 16 * ei + 4 * g) = ov;
        }
    }
}

// ---------------- proj GEMM: LDS-staged 64x64 tile, BK=32, global_load_lds ----------------
// grid (jb=128, mb=6): B(Ow)-tile sharers land on one XCD (bid%8 == jb%8).
__global__ __launch_bounds__(256, 3) void k_proj(const short* __restrict__ wpb,
                                                 const short* __restrict__ Ow,
                                                 const float* __restrict__ s_p,
                                                 const float* __restrict__ t_p,
                                                 float* __restrict__ out) {
    __shared__ short AB[2][4096];  // A 2048 shorts + B 2048 shorts per buffer
    const int t = threadIdx.x, lane = t & 63, w = t >> 6;
    const int g = lane >> 4, l15 = lane & 15;
    const int wr = w >> 1, wc = w & 1;
    const int jb = blockIdx.x, mb = blockIdx.y;

    const int cr = t >> 2, cu = t & 3;
    const int cperm = 8 * (cu ^ (cr & 3));
    const short* gA = wpb + (size_t)(mb * 64 + cr) * 512 + cperm;
    const short* gB = Ow + (size_t)((size_t)jb * 64 + cr) * 512 + cperm;

    f32x4 acc[2][2];
#pragma unroll
    for (int mi = 0; mi < 2; ++mi)
#pragma unroll
        for (int ni = 0; ni < 2; ++ni) acc[mi][ni] = f32x4{0.f, 0.f, 0.f, 0.f};

    const int kcol = 8 * (g ^ (l15 & 3));

    auto stage = [&](int ks, int buf) {
        short* base = AB[buf];
        gl_lds16(gA + ks * 32, base + t * 8);
        gl_lds16(gB + ks * 32, base + 2048 + t * 8);
    };

    stage(0, 0);
    __syncthreads();

    for (int ks = 0; ks < 16; ++ks) {
        if (ks < 15) stage(ks + 1, (ks + 1) & 1);
        const short* base = AB[ks & 1];
        s16x8 a[2], b[2];
#pragma unroll
        for (int mi = 0; mi < 2; ++mi)
            a[mi] = *(const s16x8*)(base + (32 * wr + 16 * mi + l15) * 32 + kcol);
#pragma unroll
        for (int ni = 0; ni < 2; ++ni)
            b[ni] = *(const s16x8*)(base + 2048 + (32 * wc + 16 * ni + l15) * 32 + kcol);
#pragma unroll
        for (int mi = 0; mi < 2; ++mi)
#pragma unroll
            for (int ni = 0; ni < 2; ++ni)
                acc[mi][ni] = mfma16(a[mi], b[ni], acc[mi][ni]);
        __syncthreads();
    }

    const int m_base = mb * 64 + 32 * wr;
    const int j_base = jb * 64 + 32 * wc;
#pragma unroll
    for (int mi = 0; mi < 2; ++mi) {
#pragma unroll
        for (int ni = 0; ni < 2; ++ni) {
            const int j = j_base + 16 * ni + l15;
            const int bb = j >> 10, n = j & 1023;
#pragma unroll
            for (int r = 0; r < 4; ++r) {
                const int c = m_base + 16 * mi + 4 * g + r;
                float v = acc[mi][ni][r] * s_p[c] + t_p[c];
                out[((size_t)bb * 384 + c) * 1024 + n] = v;
            }
        }
    }
}

extern "C" void kernel_launch(void* const* d_in, const int* in_sizes, int n_in,
                              void* d_out, int out_size, void* d_ws, size_t ws_size,
                              hipStream_t stream) {
    const float* x  = (const float*)d_in[0];
    const float* wq = (const float*)d_in[1];
    const float* gq = (const float*)d_in[2];
    const float* bq = (const float*)d_in[3];
    const float* mq = (const float*)d_in[4];
    const float* vq = (const float*)d_in[5];
    const float* wk = (const float*)d_in[6];
    const float* gk = (const float*)d_in[7];
    const float* bk = (const float*)d_in[8];
    const float* mk = (const float*)d_in[9];
    const float* vk = (const float*)d_in[10];
    const float* wv = (const float*)d_in[11];
    const float* gv = (const float*)d_in[12];
    const float* bv = (const float*)d_in[13];
    const float* mv = (const float*)d_in[14];
    const float* vv = (const float*)d_in[15];
    const float* wp = (const float*)d_in[16];
    const float* gp = (const float*)d_in[17];
    const float* bp = (const float*)d_in[18];
    const float* mp = (const float*)d_in[19];
    const float* vp = (const float*)d_in[20];
    float* out = (float*)d_out;

    char* ws = (char*)d_ws;
    size_t off = 0;
    auto alloc = [&](size_t bytes) {
        char* p = ws + off;
        off += (bytes + 255) & ~(size_t)255;
        return p;
    };
    short* xt    = (short*)alloc((size_t)8 * 1024 * 384 * 2);
    short* wqkv  = (short*)alloc((size_t)1024 * 384 * 2);
    short* wpb   = (short*)alloc((size_t)384 * 512 * 2);
    float* s_qkv = (float*)alloc(1024 * 4);
    float* t_qkv = (float*)alloc(1024 * 4);
    float* s_p   = (float*)alloc(384 * 4);
    float* t_p   = (float*)alloc(384 * 4);
    short* Qw    = (short*)alloc((size_t)8 * 8 * 1024 * 32 * 2);
    short* Kw    = (short*)alloc((size_t)8 * 8 * 1024 * 32 * 2);
    short* Vw    = (short*)alloc((size_t)8 * 8 * 64 * 1024 * 2);
    short* Ow    = (short*)alloc((size_t)8 * 1024 * 512 * 2);
    (void)ws_size; (void)in_sizes; (void)n_in; (void)out_size;

    k_prep_x<<<dim3(12, 32, 8), 256, 0, stream>>>(x, xt);
    k_prep_w<<<dim3((1024 * 384 + 384 * 512 + 255) / 256), 256, 0, stream>>>(
        wq, wk, wv, wp, wqkv, wpb,
        gq, bq, mq, vq, gk, bk, mk, vk, gv, bv, mv, vv, gp, bp, mp, vp,
        s_qkv, t_qkv, s_p, t_p);
    k_gemm_qkv<<<dim3(64, 8), 256, 0, stream>>>(wqkv, xt, s_qkv, t_qkv, Qw, Kw, Vw);
    k_attn<<<dim3(512), 256, 0, stream>>>(Qw, Kw, Vw, Ow);
    k_proj<<<dim3(128, 6), 256, 0, stream>>>(wpb, Ow, s_p, t_p, out);
}

// Round 11
// 53.738 us; speedup vs baseline: 3.9027x; 1.0942x over previous
//
#include <hip/hip_runtime.h>
#include <hip/hip_bf16.h>

#define DEVI __device__ __forceinline__

typedef __attribute__((ext_vector_type(8))) short s16x8;
typedef __attribute__((ext_vector_type(4))) short s16x4;
typedef __attribute__((ext_vector_type(4))) float f32x4;

// ---- problem constants ----
// x: (8, 384, 32, 32); heads=8, dk=32, dv=64; N=1024 tokens; Cqk=256, Cv=512
#define LOG2E 1.4426950408889634f

DEVI short f2bs(float f) {  // fp32 -> bf16 bits (RNE)
    unsigned u = __builtin_bit_cast(unsigned, f);
    unsigned r = (u + 0x7fffu + ((u >> 16) & 1u)) >> 16;
    return (short)r;
}

DEVI f32x4 mfma16(s16x8 a, s16x8 b, f32x4 c) {
    return __builtin_amdgcn_mfma_f32_16x16x32_bf16(a, b, c, 0, 0, 0);
}

// async global->LDS 16B copy; LDS dest linear in lane order, swizzle in gsrc
DEVI void gl_lds16(const short* g, short* l) {
    __builtin_amdgcn_global_load_lds(
        (const __attribute__((address_space(1))) unsigned*)(const void*)g,
        (__attribute__((address_space(3))) unsigned*)(void*)l, 16, 0, 0);
}

// ---------------- merged prep: x transpose+cvt AND weights cvt + BN fold ----------------
// blocks [0,3072): x (b,c,n) fp32 -> xt (b,n,c) bf16
// blocks [3072,5376): weights fp32->bf16 + BN fold
__global__ __launch_bounds__(256) void k_prep(
    const float* __restrict__ x, short* __restrict__ xt,
    const float* __restrict__ wq, const float* __restrict__ wk,
    const float* __restrict__ wv, const float* __restrict__ wp,
    short* __restrict__ wqkv, short* __restrict__ wpb,
    const float* gq, const float* bq, const float* mq, const float* vq,
    const float* gk, const float* bk, const float* mk, const float* vk,
    const float* gv, const float* bv, const float* mv, const float* vv,
    const float* gp, const float* bp, const float* mp, const float* vp,
    float* s_qkv, float* t_qkv, float* s_p, float* t_p) {
    __shared__ float tile[32][33];
    const int bid = blockIdx.x;
    const int t = threadIdx.x;
    if (bid < 3072) {
        const int ct = bid % 12, nt = (bid / 12) % 32, b = bid / 384;
        {
            const int j = t & 31, i0 = (t >> 5) * 4;
            const float* src = x + ((size_t)b * 384 + (size_t)ct * 32) * 1024 + nt * 32;
#pragma unroll
            for (int ii = 0; ii < 4; ++ii)
                tile[i0 + ii][j] = src[(size_t)(i0 + ii) * 1024 + j];
        }
        __syncthreads();
        {
            const int ii = t & 31, j0 = (t >> 5) * 4;
            short* dst = xt + ((size_t)b * 1024 + (size_t)nt * 32) * 384 + ct * 32;
#pragma unroll
            for (int jj = 0; jj < 4; ++jj)
                dst[(size_t)(j0 + jj) * 384 + ii] = f2bs(tile[ii][j0 + jj]);
        }
        return;
    }
    int i = (bid - 3072) * 256 + t;
    if (i < 1024) {
        const float *g, *bb, *mm, *vv_;
        int o = i;
        float post = 1.0f;
        if (i < 256)      { g = gq; bb = bq; mm = mq; vv_ = vq; post = LOG2E; }
        else if (i < 512) { g = gk; bb = bk; mm = mk; vv_ = vk; o = i - 256; }
        else              { g = gv; bb = bv; mm = mv; vv_ = vv; o = i - 512; }
        float s = g[o] * rsqrtf(vv_[o] + 1e-5f);
        s_qkv[i] = s * post;
        t_qkv[i] = (bb[o] - mm[o] * s) * post;
        if (i < 384) {
            float sp = gp[i] * rsqrtf(vp[i] + 1e-5f);
            s_p[i] = sp;
            t_p[i] = bp[i] - mp[i] * sp;
        }
    }
    const int NQKV = 1024 * 384;
    if (i < NQKV) {
        int o = i / 384;
        float v;
        if (o < 256)      v = wq[i];
        else if (o < 512) v = wk[i - 256 * 384];
        else              v = wv[i - 512 * 384];
        wqkv[i] = f2bs(v);
    } else {
        int j = i - NQKV;
        if (j < 384 * 512) wpb[j] = f2bs(wp[j]);
    }
}

// ---------------- QKV GEMM: LDS-staged 128x128 tile, BK=64 (2 sub-phases/barrier) ----------------
// grid (jb=64, mb=8): blocks sharing the B(x)-tile land on one XCD (bid%8 == jb%8).
// LDS row = 64 k-shorts = 8 units of 16B; global k-unit permuted by row&7.
__global__ __launch_bounds__(256, 2) void k_gemm_qkv(
    const short* __restrict__ wqkv, const short* __restrict__ xt,
    const float* __restrict__ s_qkv, const float* __restrict__ t_qkv,
    short* __restrict__ Qw, short* __restrict__ Kw, short* __restrict__ Vw) {
    __shared__ short AB[2][16384];  // A [128][64] + B [128][64] shorts per buffer
    const int t = threadIdx.x, lane = t & 63, w = t >> 6;
    const int g = lane >> 4, l15 = lane & 15;
    const int wr = w >> 1, wc = w & 1;
    const int jb = blockIdx.x, mb = blockIdx.y;

    // stage: thread t -> rows (t>>3)+32*jj (jj=0..3), unit t&7; perm const over jj
    const int ar = t >> 3, au = t & 7;
    const int aperm = 8 * (au ^ (ar & 7));
    const short* gA = wqkv + (size_t)(mb * 128 + ar) * 384 + aperm;
    const short* gB = xt + (size_t)((size_t)jb * 128 + ar) * 384 + aperm;

    f32x4 acc[4][4];
#pragma unroll
    for (int mi = 0; mi < 4; ++mi)
#pragma unroll
        for (int ni = 0; ni < 4; ++ni) acc[mi][ni] = f32x4{0.f, 0.f, 0.f, 0.f};

    auto stage = [&](int kt, int buf) {
        short* base = AB[buf];
#pragma unroll
        for (int jj = 0; jj < 4; ++jj) {
            gl_lds16(gA + (size_t)(32 * jj) * 384 + kt * 64, base + t * 8 + jj * 2048);
            gl_lds16(gB + (size_t)(32 * jj) * 384 + kt * 64, base + 8192 + t * 8 + jj * 2048);
        }
    };

    stage(0, 0);
    __syncthreads();

    for (int kt = 0; kt < 6; ++kt) {
        if (kt < 5) stage(kt + 1, (kt + 1) & 1);
        const short* base = AB[kt & 1];
#pragma unroll
        for (int ksub = 0; ksub < 2; ++ksub) {
            const int kc = 8 * ((4 * ksub + g) ^ (l15 & 7));
            s16x8 a[4], b[4];
#pragma unroll
            for (int mi = 0; mi < 4; ++mi)
                a[mi] = *(const s16x8*)(base + (64 * wr + 16 * mi + l15) * 64 + kc);
#pragma unroll
            for (int ni = 0; ni < 4; ++ni)
                b[ni] = *(const s16x8*)(base + 8192 + (64 * wc + 16 * ni + l15) * 64 + kc);
#pragma unroll
            for (int mi = 0; mi < 4; ++mi)
#pragma unroll
                for (int ni = 0; ni < 4; ++ni)
                    acc[mi][ni] = mfma16(a[mi], b[ni], acc[mi][ni]);
        }
        __syncthreads();
    }

    const int m_base = mb * 128 + 64 * wr;
    const int j_base = jb * 128 + 64 * wc;
#pragma unroll
    for (int mi = 0; mi < 4; ++mi) {
        const int o0 = m_base + 16 * mi;
#pragma unroll
        for (int ni = 0; ni < 4; ++ni) {
            const int j = j_base + 16 * ni + l15;
            const int bb = j >> 10, n = j & 1023;
            if (o0 < 512) {
                // Q/K: d consecutive over r -> vector store
                const int o = o0 + 4 * g;
                const int isK = o0 >= 256;
                const int o2 = o - (isK ? 256 : 0);
                const int h = o2 >> 5, d0 = o2 & 31;
                s16x4 ov;
#pragma unroll
                for (int r = 0; r < 4; ++r)
                    ov[r] = f2bs(acc[mi][ni][r] * s_qkv[o + r] + t_qkv[o + r]);
                short* dst = (isK ? Kw : Qw) + (((size_t)bb * 8 + h) * 1024 + n) * 32 + d0;
                *(s16x4*)dst = ov;
            } else {
#pragma unroll
                for (int r = 0; r < 4; ++r) {
                    const int o = o0 + 4 * g + r;
                    float val = acc[mi][ni][r] * s_qkv[o] + t_qkv[o];
                    const int o2 = o - 512;
                    const int h = o2 >> 6, e = o2 & 63;
                    Vw[(((size_t)bb * 8 + h) * 64 + e) * 1024 + n] = f2bs(val);
                }
            }
        }
    }
}

// ---------------- attention per (b,h): LDS-staged K/V, KVBLK=128 (2 sub-phases/barrier) ----------------
// 4 waves/block share one bh; K [128][32] 8KB + V [64][128] 16KB per buffer, dbuf 48KB.
// Permuted-K trick: S^T D-layout == PV B-layout, P stays in registers.
__global__ __launch_bounds__(256, 2) void k_attn(const short* __restrict__ Qw,
                                                 const short* __restrict__ Kw,
                                                 const short* __restrict__ Vw,
                                                 short* __restrict__ Ow) {
    __shared__ short KV[2][12288];  // K 4096 + V 8192 shorts per buffer
    const int t = threadIdx.x, lane = t & 63, w = t >> 6;
    const int g = lane >> 4, l15 = lane & 15;
    // blockIdx.x = (bh&7) + 8*(rb + 8*(bh>>3)) => all 8 rb of one bh on one XCD
    const int low3 = blockIdx.x & 7;
    const int mid = blockIdx.x >> 3;
    const int rb = mid & 7;
    const int bh = ((mid >> 3) << 3) | low3;
    const int n_base = rb * 128 + w * 32;
    const short* Qb = Qw + (size_t)bh * (1024 * 32);
    const short* Kb = Kw + (size_t)bh * (1024 * 32);
    const short* Vb = Vw + (size_t)bh * (64 * 1024);

    s16x8 qf[2];
#pragma unroll
    for (int i = 0; i < 2; ++i)
        qf[i] = *(const s16x8*)(Qb + (size_t)(n_base + 16 * i + l15) * 32 + 8 * g);

    // stage pointers: K rows t>>2 and t>>2+64 (unit t&3, perm by row&3);
    // V rows (t>>4)+16*jj (unit t&15, perm by row&7; 16|jj offsets preserve &7)
    const int skr = t >> 2, sku = t & 3;
    const short* gK = Kb + (size_t)skr * 32 + 8 * (sku ^ (skr & 3));
    const int vr = t >> 4, vu = t & 15;
    const short* gV = Vb + (size_t)vr * 1024 + 8 * (vu ^ (vr & 7));

    f32x4 oacc[2][4];
#pragma unroll
    for (int niq = 0; niq < 2; ++niq)
#pragma unroll
        for (int ei = 0; ei < 4; ++ei) oacc[niq][ei] = f32x4{0.f, 0.f, 0.f, 0.f};
    float l_part[2] = {0.f, 0.f};

    // fragment read offsets
    const int krow = 8 * (l15 >> 2) + (l15 & 3);
    const int kcol = 8 * (g ^ (l15 & 3));

    auto stage = [&](int m0, int buf) {
        short* base = KV[buf];
        gl_lds16(gK + m0 * 32, base + t * 8);
        gl_lds16(gK + (m0 + 64) * 32, base + (t + 256) * 8);
#pragma unroll
        for (int jj = 0; jj < 4; ++jj)
            gl_lds16(gV + (size_t)(16 * jj) * 1024 + m0, base + 4096 + t * 8 + jj * 2048);
    };

    stage(0, 0);
    __syncthreads();

    for (int mt = 0; mt < 8; ++mt) {
        if (mt < 7) stage((mt + 1) * 128, (mt + 1) & 1);
        const short* base = KV[mt & 1];
#pragma unroll
        for (int msub = 0; msub < 2; ++msub) {
            const int mofs = 64 * msub;
            // K fragments (permuted rows {0,4,32,36} within the 64-sub-tile)
            s16x8 kf[4];
            kf[0] = *(const s16x8*)(base + (krow + mofs + 0) * 32 + kcol);
            kf[1] = *(const s16x8*)(base + (krow + mofs + 4) * 32 + kcol);
            kf[2] = *(const s16x8*)(base + (krow + mofs + 32) * 32 + kcol);
            kf[3] = *(const s16x8*)(base + (krow + mofs + 36) * 32 + kcol);
            // V fragments: unit = 8*msub + 4*ki + g, XOR row&7
            s16x8 vb[2][4];
#pragma unroll
            for (int ki = 0; ki < 2; ++ki)
#pragma unroll
                for (int ei = 0; ei < 4; ++ei) {
                    const int row = 16 * ei + l15;
                    vb[ki][ei] = *(const s16x8*)(base + 4096 + row * 128 +
                                                 8 * ((8 * msub + 4 * ki + g) ^ (row & 7)));
                }
            // S^T
            __builtin_amdgcn_s_setprio(1);
            f32x4 st[4][2];
#pragma unroll
            for (int mik = 0; mik < 4; ++mik)
#pragma unroll
                for (int niq = 0; niq < 2; ++niq)
                    st[mik][niq] = mfma16(kf[mik], qf[niq], f32x4{0.f, 0.f, 0.f, 0.f});
            __builtin_amdgcn_s_setprio(0);
            // P = exp2(S'), l partials, pack to bf16 in registers
            s16x4 pk[4][2];
#pragma unroll
            for (int mik = 0; mik < 4; ++mik)
#pragma unroll
                for (int niq = 0; niq < 2; ++niq) {
                    float p[4];
#pragma unroll
                    for (int r = 0; r < 4; ++r) p[r] = __builtin_amdgcn_exp2f(st[mik][niq][r]);
                    l_part[niq] += (p[0] + p[1]) + (p[2] + p[3]);
#pragma unroll
                    for (int r = 0; r < 4; ++r) pk[mik][niq][r] = f2bs(p[r]);
                }
            // PV: B-frag = concat(pk[2ki], pk[2ki+1])
            __builtin_amdgcn_s_setprio(1);
#pragma unroll
            for (int ki = 0; ki < 2; ++ki)
#pragma unroll
                for (int niq = 0; niq < 2; ++niq) {
                    s16x8 pb = __builtin_shufflevector(pk[2 * ki][niq], pk[2 * ki + 1][niq],
                                                       0, 1, 2, 3, 4, 5, 6, 7);
#pragma unroll
                    for (int ei = 0; ei < 4; ++ei)
                        oacc[niq][ei] = mfma16(vb[ki][ei], pb, oacc[niq][ei]);
                }
            __builtin_amdgcn_s_setprio(0);
        }
        __syncthreads();
    }

    // l reduction across g groups (butterfly leaves full sum in every lane)
    float li[2];
#pragma unroll
    for (int niq = 0; niq < 2; ++niq) {
        float s = l_part[niq];
        s += __shfl_xor(s, 16, 64);
        s += __shfl_xor(s, 32, 64);
        li[niq] = __builtin_amdgcn_rcpf(s);
    }
    // store O^T fragments: lane holds rows e = 16ei+4g..+3, col n = n_base+16niq+l15
    const int b = bh >> 3, h = bh & 7;
#pragma unroll
    for (int niq = 0; niq < 2; ++niq) {
        const int n = n_base + 16 * niq + l15;
#pragma unroll
        for (int ei = 0; ei < 4; ++ei) {
            s16x4 ov;
#pragma unroll
            for (int r = 0; r < 4; ++r)
                ov[r] = f2bs(fmaxf(oacc[niq][ei][r] * li[niq], 0.f));
            *(s16x4*)(Ow + ((size_t)b * 1024 + n) * 512 + h * 64 + 16 * ei + 4 * g) = ov;
        }
    }
}

// ---------------- proj GEMM: LDS-staged 64x64 tile, BK=64 (2 sub-phases/barrier) ----------------
// grid (jb=128, mb=6): B(Ow)-tile sharers land on one XCD (bid%8 == jb%8).
__global__ __launch_bounds__(256, 3) void k_proj(const short* __restrict__ wpb,
                                                 const short* __restrict__ Ow,
                                                 const float* __restrict__ s_p,
                                                 const float* __restrict__ t_p,
                                                 float* __restrict__ out) {
    __shared__ short AB[2][8192];  // A [64][64] + B [64][64] shorts per buffer
    const int t = threadIdx.x, lane = t & 63, w = t >> 6;
    const int g = lane >> 4, l15 = lane & 15;
    const int wr = w >> 1, wc = w & 1;
    const int jb = blockIdx.x, mb = blockIdx.y;

    // stage: rows (t>>3)+32*jj (jj=0..1), unit t&7; perm by row&7 const over jj
    const int ar = t >> 3, au = t & 7;
    const int aperm = 8 * (au ^ (ar & 7));
    const short* gA = wpb + (size_t)(mb * 64 + ar) * 512 + aperm;
    const short* gB = Ow + (size_t)((size_t)jb * 64 + ar) * 512 + aperm;

    f32x4 acc[2][2];
#pragma unroll
    for (int mi = 0; mi < 2; ++mi)
#pragma unroll
        for (int ni = 0; ni < 2; ++ni) acc[mi][ni] = f32x4{0.f, 0.f, 0.f, 0.f};

    auto stage = [&](int kt, int buf) {
        short* base = AB[buf];
#pragma unroll
        for (int jj = 0; jj < 2; ++jj) {
            gl_lds16(gA + (size_t)(32 * jj) * 512 + kt * 64, base + t * 8 + jj * 2048);
            gl_lds16(gB + (size_t)(32 * jj) * 512 + kt * 64, base + 4096 + t * 8 + jj * 2048);
        }
    };

    stage(0, 0);
    __syncthreads();

    for (int kt = 0; kt < 8; ++kt) {
        if (kt < 7) stage(kt + 1, (kt + 1) & 1);
        const short* base = AB[kt & 1];
#pragma unroll
        for (int ksub = 0; ksub < 2; ++ksub) {
            const int kc = 8 * ((4 * ksub + g) ^ (l15 & 7));
            s16x8 a[2], b[2];
#pragma unroll
            for (int mi = 0; mi < 2; ++mi)
                a[mi] = *(const s16x8*)(base + (32 * wr + 16 * mi + l15) * 64 + kc);
#pragma unroll
            for (int ni = 0; ni < 2; ++ni)
                b[ni] = *(const s16x8*)(base + 4096 + (32 * wc + 16 * ni + l15) * 64 + kc);
#pragma unroll
            for (int mi = 0; mi < 2; ++mi)
#pragma unroll
                for (int ni = 0; ni < 2; ++ni)
                    acc[mi][ni] = mfma16(a[mi], b[ni], acc[mi][ni]);
        }
        __syncthreads();
    }

    const int m_base = mb * 64 + 32 * wr;
    const int j_base = jb * 64 + 32 * wc;
#pragma unroll
    for (int mi = 0; mi < 2; ++mi) {
#pragma unroll
        for (int ni = 0; ni < 2; ++ni) {
            const int j = j_base + 16 * ni + l15;
            const int bb = j >> 10, n = j & 1023;
#pragma unroll
            for (int r = 0; r < 4; ++r) {
                const int c = m_base + 16 * mi + 4 * g + r;
                float v = acc[mi][ni][r] * s_p[c] + t_p[c];
                out[((size_t)bb * 384 + c) * 1024 + n] = v;
            }
        }
    }
}

extern "C" void kernel_launch(void* const* d_in, const int* in_sizes, int n_in,
                              void* d_out, int out_size, void* d_ws, size_t ws_size,
                              hipStream_t stream) {
    const float* x  = (const float*)d_in[0];
    const float* wq = (const float*)d_in[1];
    const float* gq = (const float*)d_in[2];
    const float* bq = (const float*)d_in[3];
    const float* mq = (const float*)d_in[4];
    const float* vq = (const float*)d_in[5];
    const float* wk = (const float*)d_in[6];
    const float* gk = (const float*)d_in[7];
    const float* bk = (const float*)d_in[8];
    const float* mk = (const float*)d_in[9];
    const float* vk = (const float*)d_in[10];
    const float* wv = (const float*)d_in[11];
    const float* gv = (const float*)d_in[12];
    const float* bv = (const float*)d_in[13];
    const float* mv = (const float*)d_in[14];
    const float* vv = (const float*)d_in[15];
    const float* wp = (const float*)d_in[16];
    const float* gp = (const float*)d_in[17];
    const float* bp = (const float*)d_in[18];
    const float* mp = (const float*)d_in[19];
    const float* vp = (const float*)d_in[20];
    float* out = (float*)d_out;

    char* ws = (char*)d_ws;
    size_t off = 0;
    auto alloc = [&](size_t bytes) {
        char* p = ws + off;
        off += (bytes + 255) & ~(size_t)255;
        return p;
    };
    short* xt    = (short*)alloc((size_t)8 * 1024 * 384 * 2);
    short* wqkv  = (short*)alloc((size_t)1024 * 384 * 2);
    short* wpb   = (short*)alloc((size_t)384 * 512 * 2);
    float* s_qkv = (float*)alloc(1024 * 4);
    float* t_qkv = (float*)alloc(1024 * 4);
    float* s_p   = (float*)alloc(384 * 4);
    float* t_p   = (float*)alloc(384 * 4);
    short* Qw    = (short*)alloc((size_t)8 * 8 * 1024 * 32 * 2);
    short* Kw    = (short*)alloc((size_t)8 * 8 * 1024 * 32 * 2);
    short* Vw    = (short*)alloc((size_t)8 * 8 * 64 * 1024 * 2);
    short* Ow    = (short*)alloc((size_t)8 * 1024 * 512 * 2);
    (void)ws_size; (void)in_sizes; (void)n_in; (void)out_size;

    k_prep<<<dim3(3072 + 2304), 256, 0, stream>>>(
        x, xt, wq, wk, wv, wp, wqkv, wpb,
        gq, bq, mq, vq, gk, bk, mk, vk, gv, bv, mv, vv, gp, bp, mp, vp,
        s_qkv, t_qkv, s_p, t_p);
    k_gemm_qkv<<<dim3(64, 8), 256, 0, stream>>>(wqkv, xt, s_qkv, t_qkv, Qw, Kw, Vw);
    k_attn<<<dim3(512), 256, 0, stream>>>(Qw, Kw, Vw, Ow);
    k_proj<<<dim3(128, 6), 256, 0, stream>>>(wpb, Ow, s_p, t_p, out);
}

// Round 12
// 48.834 us; speedup vs baseline: 4.2946x; 1.1004x over previous
//
#include <hip/hip_runtime.h>
#include <hip/hip_bf16.h>

#define DEVI __device__ __forceinline__

typedef __attribute__((ext_vector_type(8))) short s16x8;
typedef __attribute__((ext_vector_type(4))) short s16x4;
typedef __attribute__((ext_vector_type(4))) float f32x4;

// ---- problem constants ----
// x: (8, 384, 32, 32); heads=8, dk=32, dv=64; N=1024 tokens; Cqk=256, Cv=512
#define LOG2E 1.4426950408889634f

DEVI short f2bs(float f) {  // fp32 -> bf16 bits (RNE)
    unsigned u = __builtin_bit_cast(unsigned, f);
    unsigned r = (u + 0x7fffu + ((u >> 16) & 1u)) >> 16;
    return (short)r;
}

DEVI f32x4 mfma16(s16x8 a, s16x8 b, f32x4 c) {
    return __builtin_amdgcn_mfma_f32_16x16x32_bf16(a, b, c, 0, 0, 0);
}

// async global->LDS 16B copy; LDS dest linear in lane order, swizzle in gsrc
DEVI void gl_lds16(const short* g, short* l) {
    __builtin_amdgcn_global_load_lds(
        (const __attribute__((address_space(1))) unsigned*)(const void*)g,
        (__attribute__((address_space(3))) unsigned*)(void*)l, 16, 0, 0);
}

// ---------------- merged prep: x transpose+cvt AND weights cvt + BN fold ----------------
__global__ __launch_bounds__(256) void k_prep(
    const float* __restrict__ x, short* __restrict__ xt,
    const float* __restrict__ wq, const float* __restrict__ wk,
    const float* __restrict__ wv, const float* __restrict__ wp,
    short* __restrict__ wqkv, short* __restrict__ wpb,
    const float* gq, const float* bq, const float* mq, const float* vq,
    const float* gk, const float* bk, const float* mk, const float* vk,
    const float* gv, const float* bv, const float* mv, const float* vv,
    const float* gp, const float* bp, const float* mp, const float* vp,
    float* s_qkv, float* t_qkv, float* s_p, float* t_p) {
    __shared__ float tile[32][33];
    const int bid = blockIdx.x;
    const int t = threadIdx.x;
    if (bid < 3072) {
        const int ct = bid % 12, nt = (bid / 12) % 32, b = bid / 384;
        {
            const int j = t & 31, i0 = (t >> 5) * 4;
            const float* src = x + ((size_t)b * 384 + (size_t)ct * 32) * 1024 + nt * 32;
#pragma unroll
            for (int ii = 0; ii < 4; ++ii)
                tile[i0 + ii][j] = src[(size_t)(i0 + ii) * 1024 + j];
        }
        __syncthreads();
        {
            const int ii = t & 31, j0 = (t >> 5) * 4;
            short* dst = xt + ((size_t)b * 1024 + (size_t)nt * 32) * 384 + ct * 32;
#pragma unroll
            for (int jj = 0; jj < 4; ++jj)
                dst[(size_t)(j0 + jj) * 384 + ii] = f2bs(tile[ii][j0 + jj]);
        }
        return;
    }
    int i = (bid - 3072) * 256 + t;
    if (i < 1024) {
        const float *g, *bb, *mm, *vv_;
        int o = i;
        float post = 1.0f;
        if (i < 256)      { g = gq; bb = bq; mm = mq; vv_ = vq; post = LOG2E; }
        else if (i < 512) { g = gk; bb = bk; mm = mk; vv_ = vk; o = i - 256; }
        else              { g = gv; bb = bv; mm = mv; vv_ = vv; o = i - 512; }
        float s = g[o] * rsqrtf(vv_[o] + 1e-5f);
        s_qkv[i] = s * post;
        t_qkv[i] = (bb[o] - mm[o] * s) * post;
        if (i < 384) {
            float sp = gp[i] * rsqrtf(vp[i] + 1e-5f);
            s_p[i] = sp;
            t_p[i] = bp[i] - mp[i] * sp;
        }
    }
    const int NQKV = 1024 * 384;
    if (i < NQKV) {
        int o = i / 384;
        float v;
        if (o < 256)      v = wq[i];
        else if (o < 512) v = wk[i - 256 * 384];
        else              v = wv[i - 512 * 384];
        wqkv[i] = f2bs(v);
    } else {
        int j = i - NQKV;
        if (j < 384 * 512) wpb[j] = f2bs(wp[j]);
    }
}

// ---------------- QKV GEMM: LDS-staged 128x128 tile, BK=64 (2 sub-phases/barrier) ----------------
__global__ __launch_bounds__(256, 2) void k_gemm_qkv(
    const short* __restrict__ wqkv, const short* __restrict__ xt,
    const float* __restrict__ s_qkv, const float* __restrict__ t_qkv,
    short* __restrict__ Qw, short* __restrict__ Kw, short* __restrict__ Vw) {
    __shared__ short AB[2][16384];  // A [128][64] + B [128][64] shorts per buffer
    const int t = threadIdx.x, lane = t & 63, w = t >> 6;
    const int g = lane >> 4, l15 = lane & 15;
    const int wr = w >> 1, wc = w & 1;
    const int jb = blockIdx.x, mb = blockIdx.y;

    const int ar = t >> 3, au = t & 7;
    const int aperm = 8 * (au ^ (ar & 7));
    const short* gA = wqkv + (size_t)(mb * 128 + ar) * 384 + aperm;
    const short* gB = xt + (size_t)((size_t)jb * 128 + ar) * 384 + aperm;

    f32x4 acc[4][4];
#pragma unroll
    for (int mi = 0; mi < 4; ++mi)
#pragma unroll
        for (int ni = 0; ni < 4; ++ni) acc[mi][ni] = f32x4{0.f, 0.f, 0.f, 0.f};

    auto stage = [&](int kt, int buf) {
        short* base = AB[buf];
#pragma unroll
        for (int jj = 0; jj < 4; ++jj) {
            gl_lds16(gA + (size_t)(32 * jj) * 384 + kt * 64, base + t * 8 + jj * 2048);
            gl_lds16(gB + (size_t)(32 * jj) * 384 + kt * 64, base + 8192 + t * 8 + jj * 2048);
        }
    };

    stage(0, 0);
    __syncthreads();

    for (int kt = 0; kt < 6; ++kt) {
        if (kt < 5) stage(kt + 1, (kt + 1) & 1);
        const short* base = AB[kt & 1];
#pragma unroll
        for (int ksub = 0; ksub < 2; ++ksub) {
            const int kc = 8 * ((4 * ksub + g) ^ (l15 & 7));
            s16x8 a[4], b[4];
#pragma unroll
            for (int mi = 0; mi < 4; ++mi)
                a[mi] = *(const s16x8*)(base + (64 * wr + 16 * mi + l15) * 64 + kc);
#pragma unroll
            for (int ni = 0; ni < 4; ++ni)
                b[ni] = *(const s16x8*)(base + 8192 + (64 * wc + 16 * ni + l15) * 64 + kc);
#pragma unroll
            for (int mi = 0; mi < 4; ++mi)
#pragma unroll
                for (int ni = 0; ni < 4; ++ni)
                    acc[mi][ni] = mfma16(a[mi], b[ni], acc[mi][ni]);
        }
        __syncthreads();
    }

    const int m_base = mb * 128 + 64 * wr;
    const int j_base = jb * 128 + 64 * wc;
#pragma unroll
    for (int mi = 0; mi < 4; ++mi) {
        const int o0 = m_base + 16 * mi;
#pragma unroll
        for (int ni = 0; ni < 4; ++ni) {
            const int j = j_base + 16 * ni + l15;
            const int bb = j >> 10, n = j & 1023;
            if (o0 < 512) {
                const int o = o0 + 4 * g;
                const int isK = o0 >= 256;
                const int o2 = o - (isK ? 256 : 0);
                const int h = o2 >> 5, d0 = o2 & 31;
                s16x4 ov;
#pragma unroll
                for (int r = 0; r < 4; ++r)
                    ov[r] = f2bs(acc[mi][ni][r] * s_qkv[o + r] + t_qkv[o + r]);
                short* dst = (isK ? Kw : Qw) + (((size_t)bb * 8 + h) * 1024 + n) * 32 + d0;
                *(s16x4*)dst = ov;
            } else {
#pragma unroll
                for (int r = 0; r < 4; ++r) {
                    const int o = o0 + 4 * g + r;
                    float val = acc[mi][ni][r] * s_qkv[o] + t_qkv[o];
                    const int o2 = o - 512;
                    const int h = o2 >> 6, e = o2 & 63;
                    Vw[(((size_t)bb * 8 + h) * 64 + e) * 1024 + n] = f2bs(val);
                }
            }
        }
    }
}

// ---------------- attention per (b,h): LDS-staged K/V, KVBLK=128, ones-MFMA l ----------------
// Permuted-K trick: S^T D-layout == PV B-layout, P stays in registers.
// l[n] computed by lacc = mfma(ones, pb, lacc): D[row][col] = sum_k P[k][col] -> every
// lane ends with the full softmax denominator of its column; no reduction needed.
__global__ __launch_bounds__(256, 2) void k_attn(const short* __restrict__ Qw,
                                                 const short* __restrict__ Kw,
                                                 const short* __restrict__ Vw,
                                                 short* __restrict__ Ow) {
    __shared__ short KV[2][12288];  // K 4096 + V 8192 shorts per buffer
    const int t = threadIdx.x, lane = t & 63, w = t >> 6;
    const int g = lane >> 4, l15 = lane & 15;
    const int low3 = blockIdx.x & 7;
    const int mid = blockIdx.x >> 3;
    const int rb = mid & 7;
    const int bh = ((mid >> 3) << 3) | low3;
    const int n_base = rb * 128 + w * 32;
    const short* Qb = Qw + (size_t)bh * (1024 * 32);
    const short* Kb = Kw + (size_t)bh * (1024 * 32);
    const short* Vb = Vw + (size_t)bh * (64 * 1024);

    s16x8 qf[2];
#pragma unroll
    for (int i = 0; i < 2; ++i)
        qf[i] = *(const s16x8*)(Qb + (size_t)(n_base + 16 * i + l15) * 32 + 8 * g);

    const s16x8 onesf = {0x3F80, 0x3F80, 0x3F80, 0x3F80, 0x3F80, 0x3F80, 0x3F80, 0x3F80};

    const int skr = t >> 2, sku = t & 3;
    const short* gK = Kb + (size_t)skr * 32 + 8 * (sku ^ (skr & 3));
    const int vr = t >> 4, vu = t & 15;
    const short* gV = Vb + (size_t)vr * 1024 + 8 * (vu ^ (vr & 7));

    f32x4 oacc[2][4], lacc[2];
#pragma unroll
    for (int niq = 0; niq < 2; ++niq) {
        lacc[niq] = f32x4{0.f, 0.f, 0.f, 0.f};
#pragma unroll
        for (int ei = 0; ei < 4; ++ei) oacc[niq][ei] = f32x4{0.f, 0.f, 0.f, 0.f};
    }

    const int krow = 8 * (l15 >> 2) + (l15 & 3);
    const int kcol = 8 * (g ^ (l15 & 3));

    auto stage = [&](int m0, int buf) {
        short* base = KV[buf];
        gl_lds16(gK + m0 * 32, base + t * 8);
        gl_lds16(gK + (m0 + 64) * 32, base + (t + 256) * 8);
#pragma unroll
        for (int jj = 0; jj < 4; ++jj)
            gl_lds16(gV + (size_t)(16 * jj) * 1024 + m0, base + 4096 + t * 8 + jj * 2048);
    };

    stage(0, 0);
    __syncthreads();

    for (int mt = 0; mt < 8; ++mt) {
        if (mt < 7) stage((mt + 1) * 128, (mt + 1) & 1);
        const short* base = KV[mt & 1];
#pragma unroll
        for (int msub = 0; msub < 2; ++msub) {
            const int mofs = 64 * msub;
            s16x8 kf[4];
            kf[0] = *(const s16x8*)(base + (krow + mofs + 0) * 32 + kcol);
            kf[1] = *(const s16x8*)(base + (krow + mofs + 4) * 32 + kcol);
            kf[2] = *(const s16x8*)(base + (krow + mofs + 32) * 32 + kcol);
            kf[3] = *(const s16x8*)(base + (krow + mofs + 36) * 32 + kcol);
            s16x8 vb[2][4];
#pragma unroll
            for (int ki = 0; ki < 2; ++ki)
#pragma unroll
                for (int ei = 0; ei < 4; ++ei) {
                    const int row = 16 * ei + l15;
                    vb[ki][ei] = *(const s16x8*)(base + 4096 + row * 128 +
                                                 8 * ((8 * msub + 4 * ki + g) ^ (row & 7)));
                }
            // S^T
            __builtin_amdgcn_s_setprio(1);
            f32x4 st[4][2];
#pragma unroll
            for (int mik = 0; mik < 4; ++mik)
#pragma unroll
                for (int niq = 0; niq < 2; ++niq)
                    st[mik][niq] = mfma16(kf[mik], qf[niq], f32x4{0.f, 0.f, 0.f, 0.f});
            __builtin_amdgcn_s_setprio(0);
            // P = exp2(S'); pack via __float2bfloat16 (pairs -> v_cvt_pk_bf16_f32)
            s16x4 pk[4][2];
#pragma unroll
            for (int mik = 0; mik < 4; ++mik)
#pragma unroll
                for (int niq = 0; niq < 2; ++niq) {
#pragma unroll
                    for (int r = 0; r < 4; ++r) {
                        float p = __builtin_amdgcn_exp2f(st[mik][niq][r]);
                        pk[mik][niq][r] =
                            __builtin_bit_cast(short, __float2bfloat16(p));
                    }
                }
            // PV + l: B-frag = concat(pk[2ki], pk[2ki+1]); lacc = mfma(ones, pb, lacc)
            __builtin_amdgcn_s_setprio(1);
#pragma unroll
            for (int ki = 0; ki < 2; ++ki)
#pragma unroll
                for (int niq = 0; niq < 2; ++niq) {
                    s16x8 pb = __builtin_shufflevector(pk[2 * ki][niq], pk[2 * ki + 1][niq],
                                                       0, 1, 2, 3, 4, 5, 6, 7);
                    lacc[niq] = mfma16(onesf, pb, lacc[niq]);
#pragma unroll
                    for (int ei = 0; ei < 4; ++ei)
                        oacc[niq][ei] = mfma16(vb[ki][ei], pb, oacc[niq][ei]);
                }
            __builtin_amdgcn_s_setprio(0);
        }
        __syncthreads();
    }

    // l is complete in every lane (row-broadcast by ones-MFMA)
    float li[2];
#pragma unroll
    for (int niq = 0; niq < 2; ++niq) li[niq] = __builtin_amdgcn_rcpf(lacc[niq][0]);

    const int b = bh >> 3, h = bh & 7;
#pragma unroll
    for (int niq = 0; niq < 2; ++niq) {
        const int n = n_base + 16 * niq + l15;
#pragma unroll
        for (int ei = 0; ei < 4; ++ei) {
            s16x4 ov;
#pragma unroll
            for (int r = 0; r < 4; ++r)
                ov[r] = f2bs(fmaxf(oacc[niq][ei][r] * li[niq], 0.f));
            *(s16x4*)(Ow + ((size_t)b * 1024 + n) * 512 + h * 64 + 16 * ei + 4 * g) = ov;
        }
    }
}

// ---------------- proj GEMM: LDS-staged 64x64 tile, BK=64 (2 sub-phases/barrier) ----------------
__global__ __launch_bounds__(256, 3) void k_proj(const short* __restrict__ wpb,
                                                 const short* __restrict__ Ow,
                                                 const float* __restrict__ s_p,
                                                 const float* __restrict__ t_p,
                                                 float* __restrict__ out) {
    __shared__ short AB[2][8192];
    const int t = threadIdx.x, lane = t & 63, w = t >> 6;
    const int g = lane >> 4, l15 = lane & 15;
    const int wr = w >> 1, wc = w & 1;
    const int jb = blockIdx.x, mb = blockIdx.y;

    const int ar = t >> 3, au = t & 7;
    const int aperm = 8 * (au ^ (ar & 7));
    const short* gA = wpb + (size_t)(mb * 64 + ar) * 512 + aperm;
    const short* gB = Ow + (size_t)((size_t)jb * 64 + ar) * 512 + aperm;

    f32x4 acc[2][2];
#pragma unroll
    for (int mi = 0; mi < 2; ++mi)
#pragma unroll
        for (int ni = 0; ni < 2; ++ni) acc[mi][ni] = f32x4{0.f, 0.f, 0.f, 0.f};

    auto stage = [&](int kt, int buf) {
        short* base = AB[buf];
#pragma unroll
        for (int jj = 0; jj < 2; ++jj) {
            gl_lds16(gA + (size_t)(32 * jj) * 512 + kt * 64, base + t * 8 + jj * 2048);
            gl_lds16(gB + (size_t)(32 * jj) * 512 + kt * 64, base + 4096 + t * 8 + jj * 2048);
        }
    };

    stage(0, 0);
    __syncthreads();

    for (int kt = 0; kt < 8; ++kt) {
        if (kt < 7) stage(kt + 1, (kt + 1) & 1);
        const short* base = AB[kt & 1];
#pragma unroll
        for (int ksub = 0; ksub < 2; ++ksub) {
            const int kc = 8 * ((4 * ksub + g) ^ (l15 & 7));
            s16x8 a[2], b[2];
#pragma unroll
            for (int mi = 0; mi < 2; ++mi)
                a[mi] = *(const s16x8*)(base + (32 * wr + 16 * mi + l15) * 64 + kc);
#pragma unroll
            for (int ni = 0; ni < 2; ++ni)
                b[ni] = *(const s16x8*)(base + 4096 + (32 * wc + 16 * ni + l15) * 64 + kc);
#pragma unroll
            for (int mi = 0; mi < 2; ++mi)
#pragma unroll
                for (int ni = 0; ni < 2; ++ni)
                    acc[mi][ni] = mfma16(a[mi], b[ni], acc[mi][ni]);
        }
        __syncthreads();
    }

    const int m_base = mb * 64 + 32 * wr;
    const int j_base = jb * 64 + 32 * wc;
#pragma unroll
    for (int mi = 0; mi < 2; ++mi) {
#pragma unroll
        for (int ni = 0; ni < 2; ++ni) {
            const int j = j_base + 16 * ni + l15;
            const int bb = j >> 10, n = j & 1023;
#pragma unroll
            for (int r = 0; r < 4; ++r) {
                const int c = m_base + 16 * mi + 4 * g + r;
                float v = acc[mi][ni][r] * s_p[c] + t_p[c];
                out[((size_t)bb * 384 + c) * 1024 + n] = v;
            }
        }
    }
}

extern "C" void kernel_launch(void* const* d_in, const int* in_sizes, int n_in,
                              void* d_out, int out_size, void* d_ws, size_t ws_size,
                              hipStream_t stream) {
    const float* x  = (const float*)d_in[0];
    const float* wq = (const float*)d_in[1];
    const float* gq = (const float*)d_in[2];
    const float* bq = (const float*)d_in[3];
    const float* mq = (const float*)d_in[4];
    const float* vq = (const float*)d_in[5];
    const float* wk = (const float*)d_in[6];
    const float* gk = (const float*)d_in[7];
    const float* bk = (const float*)d_in[8];
    const float* mk = (const float*)d_in[9];
    const float* vk = (const float*)d_in[10];
    const float* wv = (const float*)d_in[11];
    const float* gv = (const float*)d_in[12];
    const float* bv = (const float*)d_in[13];
    const float* mv = (const float*)d_in[14];
    const float* vv = (const float*)d_in[15];
    const float* wp = (const float*)d_in[16];
    const float* gp = (const float*)d_in[17];
    const float* bp = (const float*)d_in[18];
    const float* mp = (const float*)d_in[19];
    const float* vp = (const float*)d_in[20];
    float* out = (float*)d_out;

    char* ws = (char*)d_ws;
    size_t off = 0;
    auto alloc = [&](size_t bytes) {
        char* p = ws + off;
        off += (bytes + 255) & ~(size_t)255;
        return p;
    };
    short* xt    = (short*)alloc((size_t)8 * 1024 * 384 * 2);
    short* wqkv  = (short*)alloc((size_t)1024 * 384 * 2);
    short* wpb   = (short*)alloc((size_t)384 * 512 * 2);
    float* s_qkv = (float*)alloc(1024 * 4);
    float* t_qkv = (float*)alloc(1024 * 4);
    float* s_p   = (float*)alloc(384 * 4);
    float* t_p   = (float*)alloc(384 * 4);
    short* Qw    = (short*)alloc((size_t)8 * 8 * 1024 * 32 * 2);
    short* Kw    = (short*)alloc((size_t)8 * 8 * 1024 * 32 * 2);
    short* Vw    = (short*)alloc((size_t)8 * 8 * 64 * 1024 * 2);
    short* Ow    = (short*)alloc((size_t)8 * 1024 * 512 * 2);
    (void)ws_size; (void)in_sizes; (void)n_in; (void)out_size;

    k_prep<<<dim3(3072 + 2304), 256, 0, stream>>>(
        x, xt, wq, wk, wv, wp, wqkv, wpb,
        gq, bq, mq, vq, gk, bk, mk, vk, gv, bv, mv, vv, gp, bp, mp, vp,
        s_qkv, t_qkv, s_p, t_p);
    k_gemm_qkv<<<dim3(64, 8), 256, 0, stream>>>(wqkv, xt, s_qkv, t_qkv, Qw, Kw, Vw);
    k_attn<<<dim3(512), 256, 0, stream>>>(Qw, Kw, Vw, Ow);
    k_proj<<<dim3(128, 6), 256, 0, stream>>>(wpb, Ow, s_p, t_p, out);
}